// Round 1
// baseline (219.971 us; speedup 1.0000x reference)
//
#include <hip/hip_runtime.h>
#include <hip/hip_bf16.h>
#include <math.h>

#define SEQ 2048
#define DM  2048
#define NH  16
#define HD  128
#define SCALE 0.08838834764831845f

typedef __bf16 bf16_t;
typedef __bf16 bf16x8 __attribute__((ext_vector_type(8)));
typedef __bf16 bf16x4 __attribute__((ext_vector_type(4)));
typedef float  f32x4  __attribute__((ext_vector_type(4)));

typedef const __attribute__((address_space(1))) void* gas_ptr;
typedef __attribute__((address_space(3))) void* las_ptr;

__device__ __forceinline__ void gload_lds16(const void* g, void* l) {
    __builtin_amdgcn_global_load_lds((gas_ptr)g, (las_ptr)l, 16, 0, 0);
}

__device__ __forceinline__ f32x4 mfma_bf16(bf16x8 a, bf16x8 b, f32x4 c) {
    return __builtin_amdgcn_mfma_f32_16x16x32_bf16(a, b, c, 0, 0, 0);
}

// LDS tile with 64 bf16 per row (128B): chunk (16B) XOR-swizzled by row&7
__device__ __forceinline__ bf16x8 read_frag64(const bf16_t* lds, int row, int k) {
    int chunk = (k >> 3) ^ (row & 7);
    return *(const bf16x8*)(lds + row * 64 + chunk * 8);
}
// LDS tile with 128 bf16 per row (256B): low 3 chunk bits swizzled
__device__ __forceinline__ bf16x8 read_frag128(const bf16_t* lds, int row, int k) {
    int chunk = k >> 3;
    chunk = (chunk & 8) | ((chunk ^ row) & 7);
    return *(const bf16x8*)(lds + row * 128 + chunk * 8);
}

// ---------------- fp32 -> bf16 conversion (5 arrays of 2048*2048) -------------
__global__ __launch_bounds__(256) void cvt5(
    const float* __restrict__ s0, const float* __restrict__ s1,
    const float* __restrict__ s2, const float* __restrict__ s3,
    const float* __restrict__ s4,
    bf16_t* __restrict__ d0, bf16_t* __restrict__ d1, bf16_t* __restrict__ d2,
    bf16_t* __restrict__ d3, bf16_t* __restrict__ d4)
{
    int which = blockIdx.y;
    const float* s; bf16_t* d;
    switch (which) {
        case 0: s = s0; d = d0; break;
        case 1: s = s1; d = d1; break;
        case 2: s = s2; d = d2; break;
        case 3: s = s3; d = d3; break;
        default: s = s4; d = d4; break;
    }
    size_t idx = ((size_t)blockIdx.x * 256 + threadIdx.x) * 4;
    float4 v = *(const float4*)(s + idx);
    bf16x4 o = { (bf16_t)v.x, (bf16_t)v.y, (bf16_t)v.z, (bf16_t)v.w };
    *(bf16x4*)(d + idx) = o;
}

// ---------------- GEMM C = A(MxK) * B(NxK)^T, 128x128 tile, BK=64 ------------
// MODE 0: fused QKV (grid.y 0..47, sel = y>>4): RoPE epilogue for Q,K; V transposed
// MODE 1: final projection, fp32 output
template<int MODE>
__global__ __launch_bounds__(256) void gemm_k(
    const bf16_t* __restrict__ A,
    const bf16_t* __restrict__ B0, const bf16_t* __restrict__ B1,
    const bf16_t* __restrict__ B2,
    bf16_t* __restrict__ Oq, bf16_t* __restrict__ Ok, bf16_t* __restrict__ Ov,
    float* __restrict__ Of,
    const float* __restrict__ fcos, const float* __restrict__ fsin)
{
    __shared__ bf16_t lA[128 * 64];
    __shared__ bf16_t lB[128 * 64];

    const int tid = threadIdx.x;
    const int lane = tid & 63;
    const int w = tid >> 6;
    const int wm = w >> 1, wn = w & 1;
    const int g = lane >> 4, r15 = lane & 15;

    const int bm = blockIdx.x;
    int sel, bn;
    const bf16_t* Bp;
    if (MODE == 0) {
        int bny = blockIdx.y;
        sel = bny >> 4; bn = bny & 15;
        Bp = (sel == 0) ? B0 : (sel == 1) ? B1 : B2;
    } else {
        sel = 3; bn = blockIdx.y; Bp = B0;
    }

    f32x4 acc[4][4] = {};

    const size_t arow0 = (size_t)bm * 128;
    const size_t brow0 = (size_t)bn * 128;

    for (int kt = 0; kt < DM / 64; ++kt) {
        const int k0 = kt * 64;
        #pragma unroll
        for (int i = 0; i < 4; ++i) {
            int c = i * 256 + tid;
            int row = c >> 3;
            int ck = (c ^ row) & 7;               // source chunk pre-swizzle
            const bf16_t* ga = A + (arow0 + row) * DM + k0 + ck * 8;
            gload_lds16(ga, (char*)lA + (i * 256 + w * 64) * 16);
            const bf16_t* gb = Bp + (brow0 + row) * DM + k0 + ck * 8;
            gload_lds16(gb, (char*)lB + (i * 256 + w * 64) * 16);
        }
        __syncthreads();
        #pragma unroll
        for (int kk = 0; kk < 2; ++kk) {
            bf16x8 af[4], bfr[4];
            #pragma unroll
            for (int m = 0; m < 4; ++m)
                af[m] = read_frag64(lA, wm * 64 + m * 16 + r15, kk * 32 + g * 8);
            #pragma unroll
            for (int n = 0; n < 4; ++n)
                bfr[n] = read_frag64(lB, wn * 64 + n * 16 + r15, kk * 32 + g * 8);
            #pragma unroll
            for (int m = 0; m < 4; ++m)
                #pragma unroll
                for (int n = 0; n < 4; ++n)
                    acc[m][n] = mfma_bf16(af[m], bfr[n], acc[m][n]);
        }
        __syncthreads();
    }

    const int r0 = bm * 128 + wm * 64;
    const int c0 = bn * 128 + wn * 64;

    if (MODE == 1) {
        #pragma unroll
        for (int m = 0; m < 4; ++m) {
            int rowb = r0 + m * 16 + g * 4;
            #pragma unroll
            for (int n = 0; n < 4; ++n) {
                int col = c0 + n * 16 + r15;
                #pragma unroll
                for (int r = 0; r < 4; ++r)
                    Of[(size_t)(rowb + r) * DM + col] = acc[m][n][r];
            }
        }
    } else if (sel == 2) {
        // V: store transposed vT[col][s], 4 consecutive s per lane -> 8B store
        #pragma unroll
        for (int m = 0; m < 4; ++m) {
            int rowb = r0 + m * 16 + g * 4;
            #pragma unroll
            for (int n = 0; n < 4; ++n) {
                int col = c0 + n * 16 + r15;
                bf16x4 pk = { (bf16_t)acc[m][n][0], (bf16_t)acc[m][n][1],
                              (bf16_t)acc[m][n][2], (bf16_t)acc[m][n][3] };
                *(bf16x4*)&Ov[(size_t)col * SEQ + rowb] = pk;
            }
        }
    } else {
        // Q or K with RoPE: pair (even,odd) cols live in adjacent lanes
        bf16_t* dst = (sel == 0) ? Oq : Ok;
        #pragma unroll
        for (int m = 0; m < 4; ++m) {
            int rowb = r0 + m * 16 + g * 4;
            #pragma unroll
            for (int n = 0; n < 4; ++n) {
                int col = c0 + n * 16 + r15;
                int f = (col & (HD - 1)) >> 1;
                float sgn = (col & 1) ? 1.0f : -1.0f;
                #pragma unroll
                for (int r = 0; r < 4; ++r) {
                    float mine = acc[m][n][r];
                    float other = __shfl_xor(mine, 1);
                    float cc = fcos[(rowb + r) * (HD / 2) + f];
                    float ss = fsin[(rowb + r) * (HD / 2) + f];
                    float o = mine * cc + sgn * other * ss;
                    dst[(size_t)(rowb + r) * DM + col] = (bf16_t)o;
                }
            }
        }
    }
}

// ---------------- blockwise attention ----------------------------------------
// grid (32 q-blocks, 16 heads), 4 waves; per-64-block max normalization (as ref)
__global__ __launch_bounds__(256) void attn_k(
    const bf16_t* __restrict__ Q, const bf16_t* __restrict__ Kb,
    const bf16_t* __restrict__ Vt, bf16_t* __restrict__ Ob)
{
    __shared__ bf16_t lq[64 * 128];
    __shared__ bf16_t lk[64 * 128];
    __shared__ bf16_t lv[128 * 64];
    __shared__ bf16_t lp[64 * 64];

    const int tid = threadIdx.x;
    const int lane = tid & 63;
    const int w = tid >> 6;
    const int g = lane >> 4, r15 = lane & 15;
    const int qb = blockIdx.x, h = blockIdx.y;

    // stage Q tile (64 x 128)
    #pragma unroll
    for (int i = 0; i < 4; ++i) {
        int c = i * 256 + tid;
        int row = c >> 4, ckl = c & 15;
        int ck = (ckl & 8) | ((ckl ^ row) & 7);
        const bf16_t* gq = Q + (size_t)(qb * 64 + row) * DM + h * HD + ck * 8;
        gload_lds16(gq, (char*)lq + (i * 256 + w * 64) * 16);
    }

    f32x4 oacc[8] = {};
    float Lp[4] = {0.f, 0.f, 0.f, 0.f};
    __syncthreads();

    for (int j = 0; j < SEQ / 64; ++j) {
        // stage K (64x128) and V^T (128x64)
        #pragma unroll
        for (int i = 0; i < 4; ++i) {
            int c = i * 256 + tid;
            int row = c >> 4, ckl = c & 15;
            int ck = (ckl & 8) | ((ckl ^ row) & 7);
            const bf16_t* gk = Kb + (size_t)(j * 64 + row) * DM + h * HD + ck * 8;
            gload_lds16(gk, (char*)lk + (i * 256 + w * 64) * 16);
        }
        #pragma unroll
        for (int i = 0; i < 4; ++i) {
            int c = i * 256 + tid;
            int row = c >> 3;
            int ck = (c ^ row) & 7;
            const bf16_t* gv = Vt + (size_t)(h * HD + row) * SEQ + j * 64 + ck * 8;
            gload_lds16(gv, (char*)lv + (i * 256 + w * 64) * 16);
        }
        __syncthreads();

        // QK^T: this wave owns q-rows w*16..w*16+15
        f32x4 sacc[4] = {};
        #pragma unroll
        for (int ks = 0; ks < 4; ++ks) {
            bf16x8 aq = read_frag128(lq, w * 16 + r15, ks * 32 + g * 8);
            #pragma unroll
            for (int n = 0; n < 4; ++n) {
                bf16x8 bk = read_frag128(lk, n * 16 + r15, ks * 32 + g * 8);
                sacc[n] = mfma_bf16(aq, bk, sacc[n]);
            }
        }

        // per-block row max, exp, L accumulation  (row = w*16 + g*4 + r)
        float p[4][4];
        #pragma unroll
        for (int r = 0; r < 4; ++r) {
            float mx = fmaxf(fmaxf(sacc[0][r], sacc[1][r]),
                             fmaxf(sacc[2][r], sacc[3][r]));
            mx = fmaxf(mx, __shfl_xor(mx, 1));
            mx = fmaxf(mx, __shfl_xor(mx, 2));
            mx = fmaxf(mx, __shfl_xor(mx, 4));
            mx = fmaxf(mx, __shfl_xor(mx, 8));
            #pragma unroll
            for (int n = 0; n < 4; ++n) {
                float pv = __expf((sacc[n][r] - mx) * SCALE);
                p[n][r] = pv;
                Lp[r] += pv;
            }
        }
        // write P tile (bf16, swizzled); wave writes/reads only its own 16 rows
        #pragma unroll
        for (int n = 0; n < 4; ++n)
            #pragma unroll
            for (int r = 0; r < 4; ++r) {
                int row = w * 16 + g * 4 + r;
                int col = n * 16 + r15;
                int chunk = (col >> 3) ^ (row & 7);
                lp[row * 64 + chunk * 8 + (col & 7)] = (bf16_t)p[n][r];
            }

        // PV: O += P * V
        #pragma unroll
        for (int ks = 0; ks < 2; ++ks) {
            bf16x8 ap = read_frag64(lp, w * 16 + r15, ks * 32 + g * 8);
            #pragma unroll
            for (int n = 0; n < 8; ++n) {
                bf16x8 bv = read_frag64(lv, n * 16 + r15, ks * 32 + g * 8);
                oacc[n] = mfma_bf16(ap, bv, oacc[n]);
            }
        }
        __syncthreads();
    }

    // reduce L across the 16-lane group, normalize, store bf16
    #pragma unroll
    for (int r = 0; r < 4; ++r) {
        float L = Lp[r];
        L += __shfl_xor(L, 1);
        L += __shfl_xor(L, 2);
        L += __shfl_xor(L, 4);
        L += __shfl_xor(L, 8);
        Lp[r] = 1.0f / (L + 1e-6f);
    }
    #pragma unroll
    for (int n = 0; n < 8; ++n) {
        int col = h * HD + n * 16 + r15;
        int rowb = qb * 64 + w * 16 + g * 4;
        #pragma unroll
        for (int r = 0; r < 4; ++r)
            Ob[(size_t)(rowb + r) * DM + col] = (bf16_t)(oacc[n][r] * Lp[r]);
    }
}

extern "C" void kernel_launch(void* const* d_in, const int* in_sizes, int n_in,
                              void* d_out, int out_size, void* d_ws, size_t ws_size,
                              hipStream_t stream)
{
    const float* x    = (const float*)d_in[0];
    const float* fcos = (const float*)d_in[1];
    const float* fsin = (const float*)d_in[2];
    const float* Wq   = (const float*)d_in[3];
    const float* Wk   = (const float*)d_in[4];
    const float* Wv   = (const float*)d_in[5];
    const float* Wo   = (const float*)d_in[6];
    float* out = (float*)d_out;

    const size_t NE = (size_t)DM * SEQ;
    bf16_t* ws  = (bf16_t*)d_ws;
    bf16_t* xb  = ws;
    bf16_t* wqb = ws + 1 * NE;
    bf16_t* wkb = ws + 2 * NE;
    bf16_t* wvb = ws + 3 * NE;
    bf16_t* wob = ws + 4 * NE;
    bf16_t* qr  = ws + 5 * NE;
    bf16_t* kr  = ws + 6 * NE;
    bf16_t* vt  = ws + 7 * NE;
    bf16_t* ob  = ws + 8 * NE;

    hipLaunchKernelGGL(cvt5, dim3(4096, 5), dim3(256), 0, stream,
                       x, Wq, Wk, Wv, Wo, xb, wqb, wkb, wvb, wob);

    hipLaunchKernelGGL(HIP_KERNEL_NAME(gemm_k<0>), dim3(16, 48), dim3(256), 0, stream,
                       xb, wqb, wkb, wvb, qr, kr, vt, (float*)nullptr, fcos, fsin);

    hipLaunchKernelGGL(attn_k, dim3(32, 16), dim3(256), 0, stream,
                       qr, kr, vt, ob);

    hipLaunchKernelGGL(HIP_KERNEL_NAME(gemm_k<1>), dim3(16, 16), dim3(256), 0, stream,
                       ob, wob, (bf16_t*)nullptr, (bf16_t*)nullptr,
                       (bf16_t*)nullptr, (bf16_t*)nullptr, (bf16_t*)nullptr,
                       out, fcos, fsin);
}

// Round 2
// 203.572 us; speedup vs baseline: 1.0806x; 1.0806x over previous
//
#include <hip/hip_runtime.h>
#include <hip/hip_bf16.h>
#include <math.h>

#define SEQ 2048
#define DM  2048
#define NH  16
#define HD  128
#define SCALE 0.08838834764831845f

typedef __bf16 bf16_t;
typedef __bf16 bf16x8 __attribute__((ext_vector_type(8)));
typedef __bf16 bf16x4 __attribute__((ext_vector_type(4)));
typedef float  f32x4  __attribute__((ext_vector_type(4)));

typedef const __attribute__((address_space(1))) void* gas_ptr;
typedef __attribute__((address_space(3))) void* las_ptr;

__device__ __forceinline__ void gload_lds16(const void* g, void* l) {
    __builtin_amdgcn_global_load_lds((gas_ptr)g, (las_ptr)l, 16, 0, 0);
}

__device__ __forceinline__ f32x4 mfma_bf16(bf16x8 a, bf16x8 b, f32x4 c) {
    return __builtin_amdgcn_mfma_f32_16x16x32_bf16(a, b, c, 0, 0, 0);
}

// LDS tile with 64 bf16 per row (128B): chunk (16B) XOR-swizzled by row&7
__device__ __forceinline__ bf16x8 read_frag64(const bf16_t* lds, int row, int k) {
    int chunk = (k >> 3) ^ (row & 7);
    return *(const bf16x8*)(lds + row * 64 + chunk * 8);
}
// LDS tile with 128 bf16 per row (256B): low 3 chunk bits swizzled
__device__ __forceinline__ bf16x8 read_frag128(const bf16_t* lds, int row, int k) {
    int chunk = k >> 3;
    chunk = (chunk & 8) | ((chunk ^ row) & 7);
    return *(const bf16x8*)(lds + row * 128 + chunk * 8);
}
// BK=32 tile packed 2 matrix rows per 64-bf16 LDS row, chunk-XOR by ldsrow&7
// mrow in [0,256), k in {0,8,16,24}
__device__ __forceinline__ bf16x8 read_frag32(const bf16_t* lds, int row, int k) {
    int L = row >> 1;
    int u = ((row & 1) << 2) | (k >> 3);
    int c = u ^ (L & 7);
    return *(const bf16x8*)(lds + ((L << 3) + c) * 8);
}

// ---------------- fp32 -> bf16 conversion (5 arrays of 2048*2048) -------------
__global__ __launch_bounds__(256) void cvt5(
    const float* __restrict__ s0, const float* __restrict__ s1,
    const float* __restrict__ s2, const float* __restrict__ s3,
    const float* __restrict__ s4,
    bf16_t* __restrict__ d0, bf16_t* __restrict__ d1, bf16_t* __restrict__ d2,
    bf16_t* __restrict__ d3, bf16_t* __restrict__ d4)
{
    int which = blockIdx.y;
    const float* s; bf16_t* d;
    switch (which) {
        case 0: s = s0; d = d0; break;
        case 1: s = s1; d = d1; break;
        case 2: s = s2; d = d2; break;
        case 3: s = s3; d = d3; break;
        default: s = s4; d = d4; break;
    }
    size_t idx = ((size_t)blockIdx.x * 256 + threadIdx.x) * 4;
    float4 v = *(const float4*)(s + idx);
    bf16x4 o = { (bf16_t)v.x, (bf16_t)v.y, (bf16_t)v.z, (bf16_t)v.w };
    *(bf16x4*)(d + idx) = o;
}

// ---------------- pipelined QKV GEMM: 256x256 tile, BK=32, ring-3 LDS --------
// C = A(2048xK) * B(NxK)^T for B in {Wq,Wk,Wv}; RoPE epilogue for Q,K; V^T out.
// 512 threads = 8 waves (2M x 4N); per-wave 128x64 out = 8m x 4n frags.
// 2 phases per K-tile (16 MFMA each); prefetch distance 2; vmcnt(4) counted.
__global__ __launch_bounds__(512, 2) void qkv_pipe(
    const bf16_t* __restrict__ A,
    const bf16_t* __restrict__ B0, const bf16_t* __restrict__ B1,
    const bf16_t* __restrict__ B2,
    bf16_t* __restrict__ Oq, bf16_t* __restrict__ Ok, bf16_t* __restrict__ Ov,
    const float* __restrict__ fcos, const float* __restrict__ fsin)
{
    // 3 slots x (A 8192 + B 8192) bf16 = 96 KB
    __shared__ bf16_t lds3[49152];

    const int tid = threadIdx.x;
    const int lane = tid & 63;
    const int w = tid >> 6;          // 0..7
    const int wm = w >> 2;           // 0..1
    const int wn = w & 3;            // 0..3
    const int g = lane >> 4, r15 = lane & 15;

    const int bm = blockIdx.x;       // 0..7
    const int bny = blockIdx.y;      // 0..23
    const int sel = bny >> 3;
    const int bnl = bny & 7;
    const bf16_t* Bp = (sel == 0) ? B0 : (sel == 1) ? B1 : B2;

    const size_t arow0 = (size_t)bm * 256;
    const size_t brow0 = (size_t)bnl * 256;

    // per-thread staging constants: chunk ci -> (mrow, kc) with inverse swizzle
    // part0: ci = tid, part1: ci = 512 + tid
    int ci0 = tid, ci1 = 512 + tid;
    int L0 = ci0 >> 3, u0 = (ci0 & 7) ^ (L0 & 7);
    int L1 = ci1 >> 3, u1 = (ci1 & 7) ^ (L1 & 7);
    int mrow0 = (L0 << 1) | (u0 >> 2), kc0 = u0 & 3;
    int mrow1 = (L1 << 1) | (u1 >> 2), kc1 = u1 & 3;
    const bf16_t* gA0 = A  + (arow0 + mrow0) * DM + kc0 * 8;
    const bf16_t* gA1 = A  + (arow0 + mrow1) * DM + kc1 * 8;
    const bf16_t* gB0 = Bp + (brow0 + mrow0) * DM + kc0 * 8;
    const bf16_t* gB1 = Bp + (brow0 + mrow1) * DM + kc1 * 8;
    const int dst0 = (0 * 512 + w * 64) * 16;   // byte offsets inside a slot
    const int dst1 = (1 * 512 + w * 64) * 16;

    const int NT = DM / 32;          // 64 K-tiles

    f32x4 acc[8][4] = {};

    // prologue: stage tiles 0 (slot 0) and 1 (slot 1)
    {
        char* s0a = (char*)(lds3);
        char* s0b = (char*)(lds3 + 8192);
        char* s1a = (char*)(lds3 + 16384);
        char* s1b = (char*)(lds3 + 16384 + 8192);
        gload_lds16(gA0 + 0 * 32, s0a + dst0);
        gload_lds16(gB0 + 0 * 32, s0b + dst0);
        gload_lds16(gA1 + 0 * 32, s0a + dst1);
        gload_lds16(gB1 + 0 * 32, s0b + dst1);
        gload_lds16(gA0 + 1 * 32, s1a + dst0);
        gload_lds16(gB0 + 1 * 32, s1b + dst0);
        gload_lds16(gA1 + 1 * 32, s1a + dst1);
        gload_lds16(gB1 + 1 * 32, s1b + dst1);
    }
    asm volatile("s_waitcnt vmcnt(4)" ::: "memory");
    __builtin_amdgcn_s_barrier();

    int sk = 0, sp = 2;
    for (int k = 0; k < NT; ++k) {
        const bf16_t* sA = lds3 + sk * 16384;
        const bf16_t* sB = sA + 8192;
        char* pA = (char*)(lds3 + sp * 16384);
        char* pB = pA + 8192 * 2;
        const bool pf = (k + 2 < NT);
        const int kO = (k + 2) * 32;

        // ---- phase 0: frags m0..3 + all B, stage part0, MFMA m0-3 x n0-3
        bf16x8 afrag[4], bfrag[4];
        #pragma unroll
        for (int m = 0; m < 4; ++m)
            afrag[m] = read_frag32(sA, wm * 128 + m * 16 + r15, g * 8);
        #pragma unroll
        for (int n = 0; n < 4; ++n)
            bfrag[n] = read_frag32(sB, wn * 64 + n * 16 + r15, g * 8);
        if (pf) {
            gload_lds16(gA0 + kO, pA + dst0);
            gload_lds16(gB0 + kO, pB + dst0);
        }
        __builtin_amdgcn_s_barrier();
        __builtin_amdgcn_s_setprio(1);
        #pragma unroll
        for (int m = 0; m < 4; ++m)
            #pragma unroll
            for (int n = 0; n < 4; ++n)
                acc[m][n] = mfma_bf16(afrag[m], bfrag[n], acc[m][n]);
        __builtin_amdgcn_s_setprio(0);
        __builtin_amdgcn_s_barrier();

        // ---- phase 1: frags m4..7, stage part1, vmcnt, MFMA m4-7 x n0-3
        #pragma unroll
        for (int m = 0; m < 4; ++m)
            afrag[m] = read_frag32(sA, wm * 128 + (m + 4) * 16 + r15, g * 8);
        if (pf) {
            gload_lds16(gA1 + kO, pA + dst1);
            gload_lds16(gB1 + kO, pB + dst1);
        }
        if (k < NT - 2) asm volatile("s_waitcnt vmcnt(4)" ::: "memory");
        else            asm volatile("s_waitcnt vmcnt(0)" ::: "memory");
        __builtin_amdgcn_s_barrier();
        __builtin_amdgcn_s_setprio(1);
        #pragma unroll
        for (int m = 0; m < 4; ++m)
            #pragma unroll
            for (int n = 0; n < 4; ++n)
                acc[m + 4][n] = mfma_bf16(afrag[m], bfrag[n], acc[m + 4][n]);
        __builtin_amdgcn_s_setprio(0);
        __builtin_amdgcn_s_barrier();

        sk = (sk == 2) ? 0 : sk + 1;
        sp = (sp == 2) ? 0 : sp + 1;
    }

    // ---- epilogue
    const int r0 = bm * 256 + wm * 128;
    const int c0 = bnl * 256 + wn * 64;

    if (sel == 2) {
        // V: store transposed vT[col][s]
        #pragma unroll
        for (int m = 0; m < 8; ++m) {
            int rowb = r0 + m * 16 + g * 4;
            #pragma unroll
            for (int n = 0; n < 4; ++n) {
                int col = c0 + n * 16 + r15;
                bf16x4 pk = { (bf16_t)acc[m][n][0], (bf16_t)acc[m][n][1],
                              (bf16_t)acc[m][n][2], (bf16_t)acc[m][n][3] };
                *(bf16x4*)&Ov[(size_t)col * SEQ + rowb] = pk;
            }
        }
    } else {
        bf16_t* dst = (sel == 0) ? Oq : Ok;
        #pragma unroll
        for (int m = 0; m < 8; ++m) {
            int rowb = r0 + m * 16 + g * 4;
            #pragma unroll
            for (int n = 0; n < 4; ++n) {
                int col = c0 + n * 16 + r15;
                int f = (col & (HD - 1)) >> 1;
                float sgn = (col & 1) ? 1.0f : -1.0f;
                #pragma unroll
                for (int r = 0; r < 4; ++r) {
                    float mine = acc[m][n][r];
                    float other = __shfl_xor(mine, 1);
                    float cc = fcos[(rowb + r) * (HD / 2) + f];
                    float ss = fsin[(rowb + r) * (HD / 2) + f];
                    float o = mine * cc + sgn * other * ss;
                    dst[(size_t)(rowb + r) * DM + col] = (bf16_t)o;
                }
            }
        }
    }
}

// ---------------- GEMM C = A(MxK) * B(NxK)^T, 128x128 tile, BK=64 ------------
// MODE 1 only now: final projection, fp32 output
template<int MODE>
__global__ __launch_bounds__(256) void gemm_k(
    const bf16_t* __restrict__ A,
    const bf16_t* __restrict__ B0, const bf16_t* __restrict__ B1,
    const bf16_t* __restrict__ B2,
    bf16_t* __restrict__ Oq, bf16_t* __restrict__ Ok, bf16_t* __restrict__ Ov,
    float* __restrict__ Of,
    const float* __restrict__ fcos, const float* __restrict__ fsin)
{
    __shared__ bf16_t lA[128 * 64];
    __shared__ bf16_t lB[128 * 64];

    const int tid = threadIdx.x;
    const int lane = tid & 63;
    const int w = tid >> 6;
    const int wm = w >> 1, wn = w & 1;
    const int g = lane >> 4, r15 = lane & 15;

    const int bm = blockIdx.x;
    int sel, bn;
    const bf16_t* Bp;
    if (MODE == 0) {
        int bny = blockIdx.y;
        sel = bny >> 4; bn = bny & 15;
        Bp = (sel == 0) ? B0 : (sel == 1) ? B1 : B2;
    } else {
        sel = 3; bn = blockIdx.y; Bp = B0;
    }

    f32x4 acc[4][4] = {};

    const size_t arow0 = (size_t)bm * 128;
    const size_t brow0 = (size_t)bn * 128;

    for (int kt = 0; kt < DM / 64; ++kt) {
        const int k0 = kt * 64;
        #pragma unroll
        for (int i = 0; i < 4; ++i) {
            int c = i * 256 + tid;
            int row = c >> 3;
            int ck = (c ^ row) & 7;               // source chunk pre-swizzle
            const bf16_t* ga = A + (arow0 + row) * DM + k0 + ck * 8;
            gload_lds16(ga, (char*)lA + (i * 256 + w * 64) * 16);
            const bf16_t* gb = Bp + (brow0 + row) * DM + k0 + ck * 8;
            gload_lds16(gb, (char*)lB + (i * 256 + w * 64) * 16);
        }
        __syncthreads();
        #pragma unroll
        for (int kk = 0; kk < 2; ++kk) {
            bf16x8 af[4], bfr[4];
            #pragma unroll
            for (int m = 0; m < 4; ++m)
                af[m] = read_frag64(lA, wm * 64 + m * 16 + r15, kk * 32 + g * 8);
            #pragma unroll
            for (int n = 0; n < 4; ++n)
                bfr[n] = read_frag64(lB, wn * 64 + n * 16 + r15, kk * 32 + g * 8);
            #pragma unroll
            for (int m = 0; m < 4; ++m)
                #pragma unroll
                for (int n = 0; n < 4; ++n)
                    acc[m][n] = mfma_bf16(af[m], bfr[n], acc[m][n]);
        }
        __syncthreads();
    }

    const int r0 = bm * 128 + wm * 64;
    const int c0 = bn * 128 + wn * 64;

    if (MODE == 1) {
        #pragma unroll
        for (int m = 0; m < 4; ++m) {
            int rowb = r0 + m * 16 + g * 4;
            #pragma unroll
            for (int n = 0; n < 4; ++n) {
                int col = c0 + n * 16 + r15;
                #pragma unroll
                for (int r = 0; r < 4; ++r)
                    Of[(size_t)(rowb + r) * DM + col] = acc[m][n][r];
            }
        }
    }
}

// ---------------- blockwise attention ----------------------------------------
__global__ __launch_bounds__(256) void attn_k(
    const bf16_t* __restrict__ Q, const bf16_t* __restrict__ Kb,
    const bf16_t* __restrict__ Vt, bf16_t* __restrict__ Ob)
{
    __shared__ bf16_t lq[64 * 128];
    __shared__ bf16_t lk[64 * 128];
    __shared__ bf16_t lv[128 * 64];
    __shared__ bf16_t lp[64 * 64];

    const int tid = threadIdx.x;
    const int lane = tid & 63;
    const int w = tid >> 6;
    const int g = lane >> 4, r15 = lane & 15;
    const int qb = blockIdx.x, h = blockIdx.y;

    #pragma unroll
    for (int i = 0; i < 4; ++i) {
        int c = i * 256 + tid;
        int row = c >> 4, ckl = c & 15;
        int ck = (ckl & 8) | ((ckl ^ row) & 7);
        const bf16_t* gq = Q + (size_t)(qb * 64 + row) * DM + h * HD + ck * 8;
        gload_lds16(gq, (char*)lq + (i * 256 + w * 64) * 16);
    }

    f32x4 oacc[8] = {};
    float Lp[4] = {0.f, 0.f, 0.f, 0.f};
    __syncthreads();

    for (int j = 0; j < SEQ / 64; ++j) {
        #pragma unroll
        for (int i = 0; i < 4; ++i) {
            int c = i * 256 + tid;
            int row = c >> 4, ckl = c & 15;
            int ck = (ckl & 8) | ((ckl ^ row) & 7);
            const bf16_t* gk = Kb + (size_t)(j * 64 + row) * DM + h * HD + ck * 8;
            gload_lds16(gk, (char*)lk + (i * 256 + w * 64) * 16);
        }
        #pragma unroll
        for (int i = 0; i < 4; ++i) {
            int c = i * 256 + tid;
            int row = c >> 3;
            int ck = (c ^ row) & 7;
            const bf16_t* gv = Vt + (size_t)(h * HD + row) * SEQ + j * 64 + ck * 8;
            gload_lds16(gv, (char*)lv + (i * 256 + w * 64) * 16);
        }
        __syncthreads();

        f32x4 sacc[4] = {};
        #pragma unroll
        for (int ks = 0; ks < 4; ++ks) {
            bf16x8 aq = read_frag128(lq, w * 16 + r15, ks * 32 + g * 8);
            #pragma unroll
            for (int n = 0; n < 4; ++n) {
                bf16x8 bk = read_frag128(lk, n * 16 + r15, ks * 32 + g * 8);
                sacc[n] = mfma_bf16(aq, bk, sacc[n]);
            }
        }

        float p[4][4];
        #pragma unroll
        for (int r = 0; r < 4; ++r) {
            float mx = fmaxf(fmaxf(sacc[0][r], sacc[1][r]),
                             fmaxf(sacc[2][r], sacc[3][r]));
            mx = fmaxf(mx, __shfl_xor(mx, 1));
            mx = fmaxf(mx, __shfl_xor(mx, 2));
            mx = fmaxf(mx, __shfl_xor(mx, 4));
            mx = fmaxf(mx, __shfl_xor(mx, 8));
            #pragma unroll
            for (int n = 0; n < 4; ++n) {
                float pv = __expf((sacc[n][r] - mx) * SCALE);
                p[n][r] = pv;
                Lp[r] += pv;
            }
        }
        #pragma unroll
        for (int n = 0; n < 4; ++n)
            #pragma unroll
            for (int r = 0; r < 4; ++r) {
                int row = w * 16 + g * 4 + r;
                int col = n * 16 + r15;
                int chunk = (col >> 3) ^ (row & 7);
                lp[row * 64 + chunk * 8 + (col & 7)] = (bf16_t)p[n][r];
            }

        #pragma unroll
        for (int ks = 0; ks < 2; ++ks) {
            bf16x8 ap = read_frag64(lp, w * 16 + r15, ks * 32 + g * 8);
            #pragma unroll
            for (int n = 0; n < 8; ++n) {
                bf16x8 bv = read_frag64(lv, n * 16 + r15, ks * 32 + g * 8);
                oacc[n] = mfma_bf16(ap, bv, oacc[n]);
            }
        }
        __syncthreads();
    }

    #pragma unroll
    for (int r = 0; r < 4; ++r) {
        float L = Lp[r];
        L += __shfl_xor(L, 1);
        L += __shfl_xor(L, 2);
        L += __shfl_xor(L, 4);
        L += __shfl_xor(L, 8);
        Lp[r] = 1.0f / (L + 1e-6f);
    }
    #pragma unroll
    for (int n = 0; n < 8; ++n) {
        int col = h * HD + n * 16 + r15;
        int rowb = qb * 64 + w * 16 + g * 4;
        #pragma unroll
        for (int r = 0; r < 4; ++r)
            Ob[(size_t)(rowb + r) * DM + col] = (bf16_t)(oacc[n][r] * Lp[r]);
    }
}

extern "C" void kernel_launch(void* const* d_in, const int* in_sizes, int n_in,
                              void* d_out, int out_size, void* d_ws, size_t ws_size,
                              hipStream_t stream)
{
    const float* x    = (const float*)d_in[0];
    const float* fcos = (const float*)d_in[1];
    const float* fsin = (const float*)d_in[2];
    const float* Wq   = (const float*)d_in[3];
    const float* Wk   = (const float*)d_in[4];
    const float* Wv   = (const float*)d_in[5];
    const float* Wo   = (const float*)d_in[6];
    float* out = (float*)d_out;

    const size_t NE = (size_t)DM * SEQ;
    bf16_t* ws  = (bf16_t*)d_ws;
    bf16_t* xb  = ws;
    bf16_t* wqb = ws + 1 * NE;
    bf16_t* wkb = ws + 2 * NE;
    bf16_t* wvb = ws + 3 * NE;
    bf16_t* wob = ws + 4 * NE;
    bf16_t* qr  = ws + 5 * NE;
    bf16_t* kr  = ws + 6 * NE;
    bf16_t* vt  = ws + 7 * NE;
    bf16_t* ob  = ws + 8 * NE;

    hipLaunchKernelGGL(cvt5, dim3(4096, 5), dim3(256), 0, stream,
                       x, Wq, Wk, Wv, Wo, xb, wqb, wkb, wvb, wob);

    hipLaunchKernelGGL(qkv_pipe, dim3(8, 24), dim3(512), 0, stream,
                       xb, wqb, wkb, wvb, qr, kr, vt, fcos, fsin);

    hipLaunchKernelGGL(attn_k, dim3(32, 16), dim3(256), 0, stream,
                       qr, kr, vt, ob);

    hipLaunchKernelGGL(HIP_KERNEL_NAME(gemm_k<1>), dim3(16, 16), dim3(256), 0, stream,
                       ob, wob, (bf16_t*)nullptr, (bf16_t*)nullptr,
                       (bf16_t*)nullptr, (bf16_t*)nullptr, (bf16_t*)nullptr,
                       out, fcos, fsin);
}

// Round 5
// 189.114 us; speedup vs baseline: 1.1632x; 1.0764x over previous
//
#include <hip/hip_runtime.h>
#include <hip/hip_bf16.h>
#include <math.h>

#define SEQ 2048
#define DM  2048
#define NH  16
#define HD  128
#define SCALE 0.08838834764831845f

typedef __bf16 bf16_t;
typedef __bf16 bf16x8 __attribute__((ext_vector_type(8)));
typedef __bf16 bf16x4 __attribute__((ext_vector_type(4)));
typedef float  f32x4  __attribute__((ext_vector_type(4)));
typedef int    i32x4  __attribute__((ext_vector_type(4)));

typedef const __attribute__((address_space(1))) void* gas_ptr;
typedef __attribute__((address_space(3))) void* las_ptr;

__device__ __forceinline__ void gload_lds16(const void* g, void* l) {
    __builtin_amdgcn_global_load_lds((gas_ptr)g, (las_ptr)l, 16, 0, 0);
}

__device__ __forceinline__ f32x4 mfma_bf16(bf16x8 a, bf16x8 b, f32x4 c) {
    return __builtin_amdgcn_mfma_f32_16x16x32_bf16(a, b, c, 0, 0, 0);
}

__device__ __forceinline__ unsigned cvtpk_bf16(float lo, float hi) {
    unsigned d;
    asm("v_cvt_pk_bf16_f32 %0, %1, %2" : "=v"(d) : "v"(lo), "v"(hi));
    return d;
}

// LDS tile with 64 bf16 per row (128B): chunk (16B) XOR-swizzled by row&7
__device__ __forceinline__ bf16x8 read_frag64(const bf16_t* lds, int row, int k) {
    int chunk = (k >> 3) ^ (row & 7);
    return *(const bf16x8*)(lds + row * 64 + chunk * 8);
}
// LDS tile with 128 bf16 per row (256B): low 3 chunk bits swizzled
__device__ __forceinline__ bf16x8 read_frag128(const bf16_t* lds, int row, int k) {
    int chunk = k >> 3;
    chunk = (chunk & 8) | ((chunk ^ row) & 7);
    return *(const bf16x8*)(lds + row * 128 + chunk * 8);
}
// BK=32 tile packed 2 matrix rows per 64-bf16 LDS row, chunk-XOR by ldsrow&7
__device__ __forceinline__ bf16x8 read_frag32(const bf16_t* lds, int row, int k) {
    int L = row >> 1;
    int u = ((row & 1) << 2) | (k >> 3);
    int c = u ^ (L & 7);
    return *(const bf16x8*)(lds + ((L << 3) + c) * 8);
}

// ---------------- fp32 -> bf16 conversion (5 arrays of 2048*2048) -------------
__global__ __launch_bounds__(256) void cvt5(
    const float* __restrict__ s0, const float* __restrict__ s1,
    const float* __restrict__ s2, const float* __restrict__ s3,
    const float* __restrict__ s4,
    bf16_t* __restrict__ d0, bf16_t* __restrict__ d1, bf16_t* __restrict__ d2,
    bf16_t* __restrict__ d3, bf16_t* __restrict__ d4)
{
    int which = blockIdx.y;
    const float* s; bf16_t* d;
    switch (which) {
        case 0: s = s0; d = d0; break;
        case 1: s = s1; d = d1; break;
        case 2: s = s2; d = d2; break;
        case 3: s = s3; d = d3; break;
        default: s = s4; d = d4; break;
    }
    size_t idx = ((size_t)blockIdx.x * 256 + threadIdx.x) * 4;
    float4 v = *(const float4*)(s + idx);
    bf16x4 o = { (bf16_t)v.x, (bf16_t)v.y, (bf16_t)v.z, (bf16_t)v.w };
    *(bf16x4*)(d + idx) = o;
}

// ---------------- pipelined QKV GEMM: 256x256 tile, BK=32, ring-3 LDS --------
__global__ __launch_bounds__(512, 2) void qkv_pipe(
    const bf16_t* __restrict__ A,
    const bf16_t* __restrict__ B0, const bf16_t* __restrict__ B1,
    const bf16_t* __restrict__ B2,
    bf16_t* __restrict__ Oq, bf16_t* __restrict__ Ok, bf16_t* __restrict__ Ov,
    const float* __restrict__ fcos, const float* __restrict__ fsin)
{
    __shared__ bf16_t lds3[49152];

    const int tid = threadIdx.x;
    const int lane = tid & 63;
    const int w = tid >> 6;
    const int wm = w >> 2;
    const int wn = w & 3;
    const int g = lane >> 4, r15 = lane & 15;

    const int bm = blockIdx.x;
    const int bny = blockIdx.y;
    const int sel = bny >> 3;
    const int bnl = bny & 7;
    const bf16_t* Bp = (sel == 0) ? B0 : (sel == 1) ? B1 : B2;

    const size_t arow0 = (size_t)bm * 256;
    const size_t brow0 = (size_t)bnl * 256;

    int ci0 = tid, ci1 = 512 + tid;
    int L0 = ci0 >> 3, u0 = (ci0 & 7) ^ (L0 & 7);
    int L1 = ci1 >> 3, u1 = (ci1 & 7) ^ (L1 & 7);
    int mrow0 = (L0 << 1) | (u0 >> 2), kc0 = u0 & 3;
    int mrow1 = (L1 << 1) | (u1 >> 2), kc1 = u1 & 3;
    const bf16_t* gA0 = A  + (arow0 + mrow0) * DM + kc0 * 8;
    const bf16_t* gA1 = A  + (arow0 + mrow1) * DM + kc1 * 8;
    const bf16_t* gB0 = Bp + (brow0 + mrow0) * DM + kc0 * 8;
    const bf16_t* gB1 = Bp + (brow0 + mrow1) * DM + kc1 * 8;
    const int dst0 = (0 * 512 + w * 64) * 16;
    const int dst1 = (1 * 512 + w * 64) * 16;

    const int NT = DM / 32;

    f32x4 acc[8][4] = {};

    {
        char* s0a = (char*)(lds3);
        char* s0b = (char*)(lds3 + 8192);
        char* s1a = (char*)(lds3 + 16384);
        char* s1b = (char*)(lds3 + 16384 + 8192);
        gload_lds16(gA0 + 0 * 32, s0a + dst0);
        gload_lds16(gB0 + 0 * 32, s0b + dst0);
        gload_lds16(gA1 + 0 * 32, s0a + dst1);
        gload_lds16(gB1 + 0 * 32, s0b + dst1);
        gload_lds16(gA0 + 1 * 32, s1a + dst0);
        gload_lds16(gB0 + 1 * 32, s1b + dst0);
        gload_lds16(gA1 + 1 * 32, s1a + dst1);
        gload_lds16(gB1 + 1 * 32, s1b + dst1);
    }
    asm volatile("s_waitcnt vmcnt(4)" ::: "memory");
    __builtin_amdgcn_s_barrier();

    int sk = 0, sp = 2;
    for (int k = 0; k < NT; ++k) {
        const bf16_t* sA = lds3 + sk * 16384;
        const bf16_t* sB = sA + 8192;
        char* pA = (char*)(lds3 + sp * 16384);
        char* pB = pA + 8192 * 2;
        const bool pf = (k + 2 < NT);
        const int kO = (k + 2) * 32;

        bf16x8 afrag[4], bfrag[4];
        #pragma unroll
        for (int m = 0; m < 4; ++m)
            afrag[m] = read_frag32(sA, wm * 128 + m * 16 + r15, g * 8);
        #pragma unroll
        for (int n = 0; n < 4; ++n)
            bfrag[n] = read_frag32(sB, wn * 64 + n * 16 + r15, g * 8);
        if (pf) {
            gload_lds16(gA0 + kO, pA + dst0);
            gload_lds16(gB0 + kO, pB + dst0);
        }
        __builtin_amdgcn_s_barrier();
        __builtin_amdgcn_s_setprio(1);
        #pragma unroll
        for (int m = 0; m < 4; ++m)
            #pragma unroll
            for (int n = 0; n < 4; ++n)
                acc[m][n] = mfma_bf16(afrag[m], bfrag[n], acc[m][n]);
        __builtin_amdgcn_s_setprio(0);
        __builtin_amdgcn_s_barrier();

        #pragma unroll
        for (int m = 0; m < 4; ++m)
            afrag[m] = read_frag32(sA, wm * 128 + (m + 4) * 16 + r15, g * 8);
        if (pf) {
            gload_lds16(gA1 + kO, pA + dst1);
            gload_lds16(gB1 + kO, pB + dst1);
        }
        if (k < NT - 2) asm volatile("s_waitcnt vmcnt(4)" ::: "memory");
        else            asm volatile("s_waitcnt vmcnt(0)" ::: "memory");
        __builtin_amdgcn_s_barrier();
        __builtin_amdgcn_s_setprio(1);
        #pragma unroll
        for (int m = 0; m < 4; ++m)
            #pragma unroll
            for (int n = 0; n < 4; ++n)
                acc[m + 4][n] = mfma_bf16(afrag[m], bfrag[n], acc[m + 4][n]);
        __builtin_amdgcn_s_setprio(0);
        __builtin_amdgcn_s_barrier();

        sk = (sk == 2) ? 0 : sk + 1;
        sp = (sp == 2) ? 0 : sp + 1;
    }

    const int r0 = bm * 256 + wm * 128;
    const int c0 = bnl * 256 + wn * 64;

    if (sel == 2) {
        #pragma unroll
        for (int m = 0; m < 8; ++m) {
            int rowb = r0 + m * 16 + g * 4;
            #pragma unroll
            for (int n = 0; n < 4; ++n) {
                int col = c0 + n * 16 + r15;
                bf16x4 pk = { (bf16_t)acc[m][n][0], (bf16_t)acc[m][n][1],
                              (bf16_t)acc[m][n][2], (bf16_t)acc[m][n][3] };
                *(bf16x4*)&Ov[(size_t)col * SEQ + rowb] = pk;
            }
        }
    } else {
        bf16_t* dst = (sel == 0) ? Oq : Ok;
        #pragma unroll
        for (int m = 0; m < 8; ++m) {
            int rowb = r0 + m * 16 + g * 4;
            #pragma unroll
            for (int n = 0; n < 4; ++n) {
                int col = c0 + n * 16 + r15;
                int f = (col & (HD - 1)) >> 1;
                float sgn = (col & 1) ? 1.0f : -1.0f;
                #pragma unroll
                for (int r = 0; r < 4; ++r) {
                    float mine = acc[m][n][r];
                    float other = __shfl_xor(mine, 1);
                    float cc = fcos[(rowb + r) * (HD / 2) + f];
                    float ss = fsin[(rowb + r) * (HD / 2) + f];
                    float o = mine * cc + sgn * other * ss;
                    dst[(size_t)(rowb + r) * DM + col] = (bf16_t)o;
                }
            }
        }
    }
}

// ---------------- final projection GEMM (128x128 tile) -----------------------
__global__ __launch_bounds__(256) void gemm_fin(
    const bf16_t* __restrict__ A, const bf16_t* __restrict__ B0,
    float* __restrict__ Of)
{
    __shared__ bf16_t lA[128 * 64];
    __shared__ bf16_t lB[128 * 64];

    const int tid = threadIdx.x;
    const int lane = tid & 63;
    const int w = tid >> 6;
    const int wm = w >> 1, wn = w & 1;
    const int g = lane >> 4, r15 = lane & 15;

    const int bm = blockIdx.x;
    const int bn = blockIdx.y;

    f32x4 acc[4][4] = {};

    const size_t arow0 = (size_t)bm * 128;
    const size_t brow0 = (size_t)bn * 128;

    for (int kt = 0; kt < DM / 64; ++kt) {
        const int k0 = kt * 64;
        #pragma unroll
        for (int i = 0; i < 4; ++i) {
            int c = i * 256 + tid;
            int row = c >> 3;
            int ck = (c ^ row) & 7;
            const bf16_t* ga = A + (arow0 + row) * DM + k0 + ck * 8;
            gload_lds16(ga, (char*)lA + (i * 256 + w * 64) * 16);
            const bf16_t* gb = B0 + (brow0 + row) * DM + k0 + ck * 8;
            gload_lds16(gb, (char*)lB + (i * 256 + w * 64) * 16);
        }
        __syncthreads();
        #pragma unroll
        for (int kk = 0; kk < 2; ++kk) {
            bf16x8 af[4], bfr[4];
            #pragma unroll
            for (int m = 0; m < 4; ++m)
                af[m] = read_frag64(lA, wm * 64 + m * 16 + r15, kk * 32 + g * 8);
            #pragma unroll
            for (int n = 0; n < 4; ++n)
                bfr[n] = read_frag64(lB, wn * 64 + n * 16 + r15, kk * 32 + g * 8);
            #pragma unroll
            for (int m = 0; m < 4; ++m)
                #pragma unroll
                for (int n = 0; n < 4; ++n)
                    acc[m][n] = mfma_bf16(af[m], bfr[n], acc[m][n]);
        }
        __syncthreads();
    }

    const int r0 = bm * 128 + wm * 64;
    const int c0 = bn * 128 + wn * 64;
    #pragma unroll
    for (int m = 0; m < 4; ++m) {
        int rowb = r0 + m * 16 + g * 4;
        #pragma unroll
        for (int n = 0; n < 4; ++n) {
            int col = c0 + n * 16 + r15;
            #pragma unroll
            for (int r = 0; r < 4; ++r)
                Of[(size_t)(rowb + r) * DM + col] = acc[m][n][r];
        }
    }
}

// ---------------- attention v2: swapped QK^T, in-register P ------------------
// grid (16 q-blocks of 128, 16 heads), 512 thr = 8 waves, wave = 16 q-rows.
// K/V double-buffered in LDS; Q in registers; single barrier per j-iter.
__global__ __launch_bounds__(512, 2) void attn_k2(
    const bf16_t* __restrict__ Q, const bf16_t* __restrict__ Kb,
    const bf16_t* __restrict__ Vt, bf16_t* __restrict__ Ob)
{
    __shared__ bf16_t lk[2 * 64 * 128];   // K tiles (double buffer), read_frag128 layout
    __shared__ bf16_t lv[2 * 128 * 64];   // V^T tiles (double buffer), read_frag64 layout

    const int tid = threadIdx.x;
    const int lane = tid & 63;
    const int w = tid >> 6;              // wave id: q-rows w*16..w*16+15
    const int g = lane >> 4, r15 = lane & 15;
    const int qb = blockIdx.x, h = blockIdx.y;

    const int lo = g & 1, hb = g >> 1;
    const int e_src = (lo << 5) + r15;   // even-parity source lane (g_s = 2*lo)
    const int o_src = e_src + 16;        // odd-parity source lane (g_s = 2*lo+1)
    const int sA = hb ? o_src : e_src;   // shfls S0,S1,S4,S5
    const int sB = hb ? e_src : o_src;   // shfls S2,S3,S6,S7

    // Q fragments (B-operand): Q[q = qb*128 + w*16 + r15][d = ks*32 + g*8 + j]
    bf16x8 qf[4];
    {
        const bf16_t* qrow = Q + (size_t)(qb * 128 + w * 16 + r15) * DM + h * HD + g * 8;
        #pragma unroll
        for (int ks = 0; ks < 4; ++ks)
            qf[ks] = *(const bf16x8*)(qrow + ks * 32);
    }

    f32x4 oacc[8] = {};
    float Lsum = 0.f;

    // K tile: 1024 16B chunks; V^T tile: 1024 16B chunks
    #define STAGE_KV(JJ, BUF)                                                     \
    {                                                                             \
        _Pragma("unroll")                                                         \
        for (int i = 0; i < 2; ++i) {                                             \
            int c = i * 512 + tid;                                                \
            int row = c >> 4, ckl = c & 15;                                       \
            int ck = (ckl & 8) | ((ckl ^ row) & 7);                               \
            const bf16_t* gk = Kb + (size_t)((JJ) * 64 + row) * DM + h * HD + ck * 8; \
            gload_lds16(gk, (char*)lk + (BUF) * 16384 + (i * 512 + w * 64) * 16); \
        }                                                                         \
        _Pragma("unroll")                                                         \
        for (int i = 0; i < 2; ++i) {                                             \
            int c = i * 512 + tid;                                                \
            int row = c >> 3;                                                     \
            int ck = (c ^ row) & 7;                                               \
            const bf16_t* gv = Vt + (size_t)(h * HD + row) * SEQ + (JJ) * 64 + ck * 8; \
            gload_lds16(gv, (char*)lv + (BUF) * 16384 + (i * 512 + w * 64) * 16); \
        }                                                                         \
    }

    STAGE_KV(0, 0);
    asm volatile("s_waitcnt vmcnt(0)" ::: "memory");
    __builtin_amdgcn_s_barrier();

    for (int j = 0; j < SEQ / 64; ++j) {
        const int cur = j & 1;
        const bf16_t* lkc = lk + cur * 8192;
        const bf16_t* lvc = lv + cur * 8192;
        if (j < SEQ / 64 - 1) STAGE_KV(j + 1, cur ^ 1);

        // ---- QK^T swapped: sacc[n][r] = S[key = n*16+g*4+r][q = w*16+r15]
        f32x4 sacc[4] = {};
        __builtin_amdgcn_s_setprio(1);
        #pragma unroll
        for (int ks = 0; ks < 4; ++ks) {
            #pragma unroll
            for (int n = 0; n < 4; ++n) {
                bf16x8 kf = read_frag128(lkc, n * 16 + r15, ks * 32 + g * 8);
                sacc[n] = mfma_bf16(kf, qf[ks], sacc[n]);
            }
        }
        __builtin_amdgcn_s_setprio(0);

        // ---- block-local softmax for q = r15 (64 keys spread over g groups)
        float mx0 = fmaxf(fmaxf(sacc[0][0], sacc[0][1]), fmaxf(sacc[0][2], sacc[0][3]));
        float mx1 = fmaxf(fmaxf(sacc[1][0], sacc[1][1]), fmaxf(sacc[1][2], sacc[1][3]));
        float mx2 = fmaxf(fmaxf(sacc[2][0], sacc[2][1]), fmaxf(sacc[2][2], sacc[2][3]));
        float mx3 = fmaxf(fmaxf(sacc[3][0], sacc[3][1]), fmaxf(sacc[3][2], sacc[3][3]));
        float mx = fmaxf(fmaxf(mx0, mx1), fmaxf(mx2, mx3));
        mx = fmaxf(mx, __shfl_xor(mx, 16));
        mx = fmaxf(mx, __shfl_xor(mx, 32));

        float p[4][4];
        float ls = 0.f;
        #pragma unroll
        for (int n = 0; n < 4; ++n)
            #pragma unroll
            for (int r = 0; r < 4; ++r) {
                float pv = __expf((sacc[n][r] - mx) * SCALE);
                p[n][r] = pv;
                ls += pv;
            }
        Lsum += ls;

        // ---- pack to bf16 dwords: D[n][h] = keys n*16 + g*4 + 2h + {0,1}
        unsigned D00 = cvtpk_bf16(p[0][0], p[0][1]), D01 = cvtpk_bf16(p[0][2], p[0][3]);
        unsigned D10 = cvtpk_bf16(p[1][0], p[1][1]), D11 = cvtpk_bf16(p[1][2], p[1][3]);
        unsigned D20 = cvtpk_bf16(p[2][0], p[2][1]), D21 = cvtpk_bf16(p[2][2], p[2][3]);
        unsigned D30 = cvtpk_bf16(p[3][0], p[3][1]), D31 = cvtpk_bf16(p[3][2], p[3][3]);

        // ---- 8-shfl conflict-free redistribution to PV A-frag layout:
        // target lane (g) needs pa0 = keys g*8..g*8+7, pa1 = keys 32+g*8..
        // Each shfl: even-g sources export D[n_lo][h], odd-g export D[n_hi][h];
        // low targets (hb=0) read sA, high read the opposite-parity source.
        unsigned r0 = __shfl((int)(lo ? D10 : D00), sA);
        unsigned r1 = __shfl((int)(lo ? D11 : D01), sA);
        unsigned r2 = __shfl((int)(lo ? D00 : D10), sB);
        unsigned r3 = __shfl((int)(lo ? D01 : D11), sB);
        unsigned r4 = __shfl((int)(lo ? D30 : D20), sA);
        unsigned r5 = __shfl((int)(lo ? D31 : D21), sA);
        unsigned r6 = __shfl((int)(lo ? D20 : D30), sB);
        unsigned r7 = __shfl((int)(lo ? D21 : D31), sB);
        i32x4 w0, w1;
        w0[0] = (int)(hb ? r2 : r0);  w0[1] = (int)(hb ? r3 : r1);
        w0[2] = (int)(hb ? r0 : r2);  w0[3] = (int)(hb ? r1 : r3);
        w1[0] = (int)(hb ? r6 : r4);  w1[1] = (int)(hb ? r7 : r5);
        w1[2] = (int)(hb ? r4 : r6);  w1[3] = (int)(hb ? r5 : r7);
        bf16x8 pa0 = __builtin_bit_cast(bf16x8, w0);
        bf16x8 pa1 = __builtin_bit_cast(bf16x8, w1);

        // ---- PV: oacc[n] += P(16q x 64k) * V(64k x 128d)
        __builtin_amdgcn_s_setprio(1);
        #pragma unroll
        for (int n = 0; n < 8; ++n) {
            bf16x8 bv = read_frag64(lvc, n * 16 + r15, g * 8);
            oacc[n] = mfma_bf16(pa0, bv, oacc[n]);
        }
        #pragma unroll
        for (int n = 0; n < 8; ++n) {
            bf16x8 bv = read_frag64(lvc, n * 16 + r15, 32 + g * 8);
            oacc[n] = mfma_bf16(pa1, bv, oacc[n]);
        }
        __builtin_amdgcn_s_setprio(0);

        asm volatile("s_waitcnt vmcnt(0)" ::: "memory");
        __builtin_amdgcn_s_barrier();
    }

    // ---- L reduce (q = r15), broadcast to O layout (q = 4g + r), store
    float L = Lsum;
    L += __shfl_xor(L, 16);
    L += __shfl_xor(L, 32);
    float inv = 1.0f / (L + 1e-6f);
    float invr[4];
    #pragma unroll
    for (int r = 0; r < 4; ++r)
        invr[r] = __shfl(inv, g * 4 + r);

    #pragma unroll
    for (int n = 0; n < 8; ++n) {
        int col = h * HD + n * 16 + r15;
        int rowb = qb * 128 + w * 16 + g * 4;
        #pragma unroll
        for (int r = 0; r < 4; ++r)
            Ob[(size_t)(rowb + r) * DM + col] = (bf16_t)(oacc[n][r] * invr[r]);
    }
}

extern "C" void kernel_launch(void* const* d_in, const int* in_sizes, int n_in,
                              void* d_out, int out_size, void* d_ws, size_t ws_size,
                              hipStream_t stream)
{
    const float* x    = (const float*)d_in[0];
    const float* fcos = (const float*)d_in[1];
    const float* fsin = (const float*)d_in[2];
    const float* Wq   = (const float*)d_in[3];
    const float* Wk   = (const float*)d_in[4];
    const float* Wv   = (const float*)d_in[5];
    const float* Wo   = (const float*)d_in[6];
    float* out = (float*)d_out;

    const size_t NE = (size_t)DM * SEQ;
    bf16_t* ws  = (bf16_t*)d_ws;
    bf16_t* xb  = ws;
    bf16_t* wqb = ws + 1 * NE;
    bf16_t* wkb = ws + 2 * NE;
    bf16_t* wvb = ws + 3 * NE;
    bf16_t* wob = ws + 4 * NE;
    bf16_t* qr  = ws + 5 * NE;
    bf16_t* kr  = ws + 6 * NE;
    bf16_t* vt  = ws + 7 * NE;
    bf16_t* ob  = ws + 8 * NE;

    hipLaunchKernelGGL(cvt5, dim3(4096, 5), dim3(256), 0, stream,
                       x, Wq, Wk, Wv, Wo, xb, wqb, wkb, wvb, wob);

    hipLaunchKernelGGL(qkv_pipe, dim3(8, 24), dim3(512), 0, stream,
                       xb, wqb, wkb, wvb, qr, kr, vt, fcos, fsin);

    hipLaunchKernelGGL(attn_k2, dim3(16, 16), dim3(512), 0, stream,
                       qr, kr, vt, ob);

    hipLaunchKernelGGL(gemm_fin, dim3(16, 16), dim3(256), 0, stream,
                       ob, wob, out);
}

// Round 6
// 183.041 us; speedup vs baseline: 1.2018x; 1.0332x over previous
//
#include <hip/hip_runtime.h>
#include <hip/hip_bf16.h>
#include <math.h>

#define SEQ 2048
#define DM  2048
#define NH  16
#define HD  128
#define SCALE 0.08838834764831845f

typedef __bf16 bf16_t;
typedef __bf16 bf16x8 __attribute__((ext_vector_type(8)));
typedef __bf16 bf16x4 __attribute__((ext_vector_type(4)));
typedef float  f32x4  __attribute__((ext_vector_type(4)));
typedef int    i32x4  __attribute__((ext_vector_type(4)));

typedef const __attribute__((address_space(1))) void* gas_ptr;
typedef __attribute__((address_space(3))) void* las_ptr;

__device__ __forceinline__ void gload_lds16(const void* g, void* l) {
    __builtin_amdgcn_global_load_lds((gas_ptr)g, (las_ptr)l, 16, 0, 0);
}

__device__ __forceinline__ f32x4 mfma_bf16(bf16x8 a, bf16x8 b, f32x4 c) {
    return __builtin_amdgcn_mfma_f32_16x16x32_bf16(a, b, c, 0, 0, 0);
}

__device__ __forceinline__ unsigned cvtpk_bf16(float lo, float hi) {
    unsigned d;
    asm("v_cvt_pk_bf16_f32 %0, %1, %2" : "=v"(d) : "v"(lo), "v"(hi));
    return d;
}

// LDS tile with 64 bf16 per row (128B): chunk (16B) XOR-swizzled by row&7
__device__ __forceinline__ bf16x8 read_frag64(const bf16_t* lds, int row, int k) {
    int chunk = (k >> 3) ^ (row & 7);
    return *(const bf16x8*)(lds + row * 64 + chunk * 8);
}
// LDS tile with 128 bf16 per row (256B): low 3 chunk bits swizzled
__device__ __forceinline__ bf16x8 read_frag128(const bf16_t* lds, int row, int k) {
    int chunk = k >> 3;
    chunk = (chunk & 8) | ((chunk ^ row) & 7);
    return *(const bf16x8*)(lds + row * 128 + chunk * 8);
}
// K-slab layout [256 rows][32 bf16], 16B slot-swizzled: phys j = kj ^ ((row>>1)&3)
__device__ __forceinline__ bf16x8 read_slab(const bf16_t* sl, int row, int g) {
    int j = g ^ ((row >> 1) & 3);
    return *(const bf16x8*)(sl + row * 32 + j * 8);
}

// ---------------- fp32 -> bf16 conversion (5 arrays of 2048*2048) -------------
__global__ __launch_bounds__(256) void cvt5(
    const float* __restrict__ s0, const float* __restrict__ s1,
    const float* __restrict__ s2, const float* __restrict__ s3,
    const float* __restrict__ s4,
    bf16_t* __restrict__ d0, bf16_t* __restrict__ d1, bf16_t* __restrict__ d2,
    bf16_t* __restrict__ d3, bf16_t* __restrict__ d4)
{
    int which = blockIdx.y;
    const float* s; bf16_t* d;
    switch (which) {
        case 0: s = s0; d = d0; break;
        case 1: s = s1; d = d1; break;
        case 2: s = s2; d = d2; break;
        case 3: s = s3; d = d3; break;
        default: s = s4; d = d4; break;
    }
    size_t idx = ((size_t)blockIdx.x * 256 + threadIdx.x) * 4;
    float4 v = *(const float4*)(s + idx);
    bf16x4 o = { (bf16_t)v.x, (bf16_t)v.y, (bf16_t)v.z, (bf16_t)v.w };
    *(bf16x4*)(d + idx) = o;
}

// ---------------- 8-phase pipelined QKV GEMM: 256x256, BK=64, 128KB LDS ------
// C = A(2048xK) * B(NxK)^T for B in {Wq,Wk,Wv}; RoPE epilogue for Q,K; V^T out.
// 512 threads = 8 waves (2M x 4N); per-wave 128x64 out = 8m x 4n frags.
// LDS: 2 buffers x {A.ks0,A.ks1,B.ks0,B.ks1} slabs of 16KB (slab = [256][32]).
// Phase = {ds_read 4/8 frags, stage 1 half-tile, [vmcnt(8)], bar,
//          setprio(1) 16 MFMA setprio(0), bar}. Stage lands 1 phase after the
//          slot's last reader; data certified 2+ phases before first read.
#define BARX() asm volatile("s_barrier" ::: "memory")
#define VMW8 asm volatile("s_waitcnt vmcnt(8)" ::: "memory")
#define VMW4 asm volatile("s_waitcnt vmcnt(4)" ::: "memory")
#define VMW0 asm volatile("s_waitcnt vmcnt(0)" ::: "memory")
#define NOGATE

__global__ __launch_bounds__(512, 2) void qkv_pipe(
    const bf16_t* __restrict__ A,
    const bf16_t* __restrict__ B0, const bf16_t* __restrict__ B1,
    const bf16_t* __restrict__ B2,
    bf16_t* __restrict__ Oq, bf16_t* __restrict__ Ok, bf16_t* __restrict__ Ov,
    const float* __restrict__ fcos, const float* __restrict__ fsin)
{
    __shared__ bf16_t lds[65536];   // 128 KB

    const int tid = threadIdx.x;
    const int lane = tid & 63;
    const int w = tid >> 6;
    const int wm = w >> 2;           // 0..1
    const int wn = w & 3;            // 0..3
    const int g4 = lane >> 4, r15 = lane & 15;

    const int bm = blockIdx.x;       // 0..7
    const int bny = blockIdx.y;      // 0..23
    const int sel = bny >> 3;
    const int bnl = bny & 7;
    const bf16_t* Bp = (sel == 0) ? B0 : (sel == 1) ? B1 : B2;

    const size_t arow0 = (size_t)bm * 256;
    const size_t brow0 = (size_t)bnl * 256;

    // staging constants: thread covers chunks c0=tid, c1=512+tid of each slab
    const int row0 = tid >> 2;                    // c0 row (c1 row = row0+128)
    const int kj0  = (tid & 3) ^ ((row0 >> 1) & 3);
    const bf16_t* pA = A  + (arow0 + row0) * DM + kj0 * 8;
    const bf16_t* pB = Bp + (brow0 + row0) * DM + kj0 * 8;
    char* ldsb = (char*)lds;
    const int off0 = tid * 16;
    const int off1 = 8192 + tid * 16;

    // HT s: tile T=s>>2, a=s&3 (0:A.ks0 1:B.ks0 2:A.ks1 3:B.ks1)
    #define STAGE_HT(S) do { if ((S) < 128) {                                   \
        const int T_ = (S) >> 2, a_ = (S) & 3;                                  \
        const int ko_ = T_ * 64 + ((a_ >> 1) << 5);                             \
        char* dst_ = ldsb + (((T_ & 1) << 16) | ((a_ & 1) << 15) | ((a_ >> 1) << 14)); \
        const bf16_t* s0_ = (a_ & 1) ? pB : pA;                                 \
        gload_lds16(s0_ + ko_, dst_ + off0);                                    \
        gload_lds16(s0_ + 128 * DM + ko_, dst_ + off1);                         \
    } } while (0)

    // element-offset slab bases
    const bf16_t* b0A0 = lds;
    const bf16_t* b0A1 = lds + 8192;
    const bf16_t* b0B0 = lds + 16384;
    const bf16_t* b0B1 = lds + 24576;
    const bf16_t* b1A0 = lds + 32768;
    const bf16_t* b1A1 = lds + 40960;
    const bf16_t* b1B0 = lds + 49152;
    const bf16_t* b1B1 = lds + 57344;

    f32x4 acc[8][4] = {};

    #define PHASE(ASL, BSL, MH, SIDX, GATE, READB)                              \
    {                                                                           \
        _Pragma("unroll")                                                       \
        for (int m = 0; m < 4; ++m)                                             \
            af[m] = read_slab((ASL), wm * 128 + (MH) * 64 + m * 16 + r15, g4);  \
        if (READB) {                                                            \
            _Pragma("unroll")                                                   \
            for (int n = 0; n < 4; ++n)                                         \
                bfr[n] = read_slab((BSL), wn * 64 + n * 16 + r15, g4);          \
        }                                                                       \
        STAGE_HT(SIDX);                                                         \
        GATE;                                                                   \
        BARX();                                                                 \
        __builtin_amdgcn_s_setprio(1);                                          \
        _Pragma("unroll")                                                       \
        for (int m = 0; m < 4; ++m)                                             \
            _Pragma("unroll")                                                   \
            for (int n = 0; n < 4; ++n)                                         \
                acc[(MH) * 4 + m][n] = mfma_bf16(af[m], bfr[n], acc[(MH) * 4 + m][n]); \
        __builtin_amdgcn_s_setprio(0);                                          \
        BARX();                                                                 \
    }

    // prologue: tile0 all 4 slabs -> buf0; tile1 ks0 slabs -> buf1
    STAGE_HT(0); STAGE_HT(1); STAGE_HT(2); STAGE_HT(3); STAGE_HT(4); STAGE_HT(5);
    VMW8;
    BARX();

    for (int i = 0; i < 15; ++i) {
        const int s0 = 6 + i * 8;
        bf16x8 af[4], bfr[4];
        PHASE(b0A0, b0B0, 0, s0 + 0, NOGATE, 1)
        PHASE(b0A0, b0B0, 1, s0 + 1, VMW8,   0)
        PHASE(b0A1, b0B1, 0, s0 + 2, NOGATE, 1)
        PHASE(b0A1, b0B1, 1, s0 + 3, VMW8,   0)
        PHASE(b1A0, b1B0, 0, s0 + 4, NOGATE, 1)
        PHASE(b1A0, b1B0, 1, s0 + 5, VMW8,   0)
        PHASE(b1A1, b1B1, 0, s0 + 6, NOGATE, 1)
        PHASE(b1A1, b1B1, 1, s0 + 7, VMW8,   0)
    }
    {   // final iter: drain gates 8 -> 4 -> 0
        const int s0 = 6 + 15 * 8;
        bf16x8 af[4], bfr[4];
        PHASE(b0A0, b0B0, 0, s0 + 0, NOGATE, 1)
        PHASE(b0A0, b0B0, 1, s0 + 1, VMW8,   0)
        PHASE(b0A1, b0B1, 0, s0 + 2, NOGATE, 1)
        PHASE(b0A1, b0B1, 1, s0 + 3, VMW4,   0)
        PHASE(b1A0, b1B0, 0, s0 + 4, NOGATE, 1)
        PHASE(b1A0, b1B0, 1, s0 + 5, VMW0,   0)
        PHASE(b1A1, b1B1, 0, s0 + 6, NOGATE, 1)
        PHASE(b1A1, b1B1, 1, s0 + 7, NOGATE, 0)
    }
    #undef PHASE
    #undef STAGE_HT

    // ---- epilogue
    const int r0 = bm * 256 + wm * 128;
    const int c0 = bnl * 256 + wn * 64;

    if (sel == 2) {
        #pragma unroll
        for (int m = 0; m < 8; ++m) {
            int rowb = r0 + m * 16 + g4 * 4;
            #pragma unroll
            for (int n = 0; n < 4; ++n) {
                int col = c0 + n * 16 + r15;
                bf16x4 pk = { (bf16_t)acc[m][n][0], (bf16_t)acc[m][n][1],
                              (bf16_t)acc[m][n][2], (bf16_t)acc[m][n][3] };
                *(bf16x4*)&Ov[(size_t)col * SEQ + rowb] = pk;
            }
        }
    } else {
        bf16_t* dst = (sel == 0) ? Oq : Ok;
        #pragma unroll
        for (int m = 0; m < 8; ++m) {
            int rowb = r0 + m * 16 + g4 * 4;
            #pragma unroll
            for (int n = 0; n < 4; ++n) {
                int col = c0 + n * 16 + r15;
                int f = (col & (HD - 1)) >> 1;
                float sgn = (col & 1) ? 1.0f : -1.0f;
                #pragma unroll
                for (int r = 0; r < 4; ++r) {
                    float mine = acc[m][n][r];
                    float other = __shfl_xor(mine, 1);
                    float cc = fcos[(rowb + r) * (HD / 2) + f];
                    float ss = fsin[(rowb + r) * (HD / 2) + f];
                    float o = mine * cc + sgn * other * ss;
                    dst[(size_t)(rowb + r) * DM + col] = (bf16_t)o;
                }
            }
        }
    }
}

// ---------------- final projection GEMM (128x128 tile) -----------------------
__global__ __launch_bounds__(256) void gemm_fin(
    const bf16_t* __restrict__ A, const bf16_t* __restrict__ B0,
    float* __restrict__ Of)
{
    __shared__ bf16_t lA[128 * 64];
    __shared__ bf16_t lB[128 * 64];

    const int tid = threadIdx.x;
    const int lane = tid & 63;
    const int w = tid >> 6;
    const int wm = w >> 1, wn = w & 1;
    const int g = lane >> 4, r15 = lane & 15;

    const int bm = blockIdx.x;
    const int bn = blockIdx.y;

    f32x4 acc[4][4] = {};

    const size_t arow0 = (size_t)bm * 128;
    const size_t brow0 = (size_t)bn * 128;

    for (int kt = 0; kt < DM / 64; ++kt) {
        const int k0 = kt * 64;
        #pragma unroll
        for (int i = 0; i < 4; ++i) {
            int c = i * 256 + tid;
            int row = c >> 3;
            int ck = (c ^ row) & 7;
            const bf16_t* ga = A + (arow0 + row) * DM + k0 + ck * 8;
            gload_lds16(ga, (char*)lA + (i * 256 + w * 64) * 16);
            const bf16_t* gb = B0 + (brow0 + row) * DM + k0 + ck * 8;
            gload_lds16(gb, (char*)lB + (i * 256 + w * 64) * 16);
        }
        __syncthreads();
        #pragma unroll
        for (int kk = 0; kk < 2; ++kk) {
            bf16x8 af[4], bfr[4];
            #pragma unroll
            for (int m = 0; m < 4; ++m)
                af[m] = read_frag64(lA, wm * 64 + m * 16 + r15, kk * 32 + g * 8);
            #pragma unroll
            for (int n = 0; n < 4; ++n)
                bfr[n] = read_frag64(lB, wn * 64 + n * 16 + r15, kk * 32 + g * 8);
            #pragma unroll
            for (int m = 0; m < 4; ++m)
                #pragma unroll
                for (int n = 0; n < 4; ++n)
                    acc[m][n] = mfma_bf16(af[m], bfr[n], acc[m][n]);
        }
        __syncthreads();
    }

    const int r0 = bm * 128 + wm * 64;
    const int c0 = bn * 128 + wn * 64;
    #pragma unroll
    for (int m = 0; m < 4; ++m) {
        int rowb = r0 + m * 16 + g * 4;
        #pragma unroll
        for (int n = 0; n < 4; ++n) {
            int col = c0 + n * 16 + r15;
            #pragma unroll
            for (int r = 0; r < 4; ++r)
                Of[(size_t)(rowb + r) * DM + col] = acc[m][n][r];
        }
    }
}

// ---------------- attention v2: swapped QK^T, in-register P ------------------
// grid (16 q-blocks of 128, 16 heads), 512 thr = 8 waves, wave = 16 q-rows.
// K/V double-buffered in LDS; Q in registers; single barrier per j-iter.
__global__ __launch_bounds__(512, 2) void attn_k2(
    const bf16_t* __restrict__ Q, const bf16_t* __restrict__ Kb,
    const bf16_t* __restrict__ Vt, bf16_t* __restrict__ Ob)
{
    __shared__ bf16_t lk[2 * 64 * 128];   // K tiles (double buffer), read_frag128 layout
    __shared__ bf16_t lv[2 * 128 * 64];   // V^T tiles (double buffer), read_frag64 layout

    const int tid = threadIdx.x;
    const int lane = tid & 63;
    const int w = tid >> 6;              // wave id: q-rows w*16..w*16+15
    const int g = lane >> 4, r15 = lane & 15;
    const int qb = blockIdx.x, h = blockIdx.y;

    const int lo = g & 1, hb = g >> 1;
    const int e_src = (lo << 5) + r15;   // even-parity source lane (g_s = 2*lo)
    const int o_src = e_src + 16;        // odd-parity source lane (g_s = 2*lo+1)
    const int sA = hb ? o_src : e_src;   // shfls S0,S1,S4,S5
    const int sB = hb ? e_src : o_src;   // shfls S2,S3,S6,S7

    // Q fragments (B-operand): Q[q = qb*128 + w*16 + r15][d = ks*32 + g*8 + j]
    bf16x8 qf[4];
    {
        const bf16_t* qrow = Q + (size_t)(qb * 128 + w * 16 + r15) * DM + h * HD + g * 8;
        #pragma unroll
        for (int ks = 0; ks < 4; ++ks)
            qf[ks] = *(const bf16x8*)(qrow + ks * 32);
    }

    f32x4 oacc[8] = {};
    float Lsum = 0.f;

    // K tile: 1024 16B chunks; V^T tile: 1024 16B chunks
    #define STAGE_KV(JJ, BUF)                                                     \
    {                                                                             \
        _Pragma("unroll")                                                         \
        for (int i = 0; i < 2; ++i) {                                             \
            int c = i * 512 + tid;                                                \
            int row = c >> 4, ckl = c & 15;                                       \
            int ck = (ckl & 8) | ((ckl ^ row) & 7);                               \
            const bf16_t* gk = Kb + (size_t)((JJ) * 64 + row) * DM + h * HD + ck * 8; \
            gload_lds16(gk, (char*)lk + (BUF) * 16384 + (i * 512 + w * 64) * 16); \
        }                                                                         \
        _Pragma("unroll")                                                         \
        for (int i = 0; i < 2; ++i) {                                             \
            int c = i * 512 + tid;                                                \
            int row = c >> 3;                                                     \
            int ck = (c ^ row) & 7;                                               \
            const bf16_t* gv = Vt + (size_t)(h * HD + row) * SEQ + (JJ) * 64 + ck * 8; \
            gload_lds16(gv, (char*)lv + (BUF) * 16384 + (i * 512 + w * 64) * 16); \
        }                                                                         \
    }

    STAGE_KV(0, 0);
    asm volatile("s_waitcnt vmcnt(0)" ::: "memory");
    __builtin_amdgcn_s_barrier();

    for (int j = 0; j < SEQ / 64; ++j) {
        const int cur = j & 1;
        const bf16_t* lkc = lk + cur * 8192;
        const bf16_t* lvc = lv + cur * 8192;
        if (j < SEQ / 64 - 1) STAGE_KV(j + 1, cur ^ 1);

        // ---- QK^T swapped: sacc[n][r] = S[key = n*16+g*4+r][q = w*16+r15]
        f32x4 sacc[4] = {};
        __builtin_amdgcn_s_setprio(1);
        #pragma unroll
        for (int ks = 0; ks < 4; ++ks) {
            #pragma unroll
            for (int n = 0; n < 4; ++n) {
                bf16x8 kf = read_frag128(lkc, n * 16 + r15, ks * 32 + g * 8);
                sacc[n] = mfma_bf16(kf, qf[ks], sacc[n]);
            }
        }
        __builtin_amdgcn_s_setprio(0);

        // ---- block-local softmax for q = r15 (64 keys spread over g groups)
        float mx0 = fmaxf(fmaxf(sacc[0][0], sacc[0][1]), fmaxf(sacc[0][2], sacc[0][3]));
        float mx1 = fmaxf(fmaxf(sacc[1][0], sacc[1][1]), fmaxf(sacc[1][2], sacc[1][3]));
        float mx2 = fmaxf(fmaxf(sacc[2][0], sacc[2][1]), fmaxf(sacc[2][2], sacc[2][3]));
        float mx3 = fmaxf(fmaxf(sacc[3][0], sacc[3][1]), fmaxf(sacc[3][2], sacc[3][3]));
        float mx = fmaxf(fmaxf(mx0, mx1), fmaxf(mx2, mx3));
        mx = fmaxf(mx, __shfl_xor(mx, 16));
        mx = fmaxf(mx, __shfl_xor(mx, 32));

        float p[4][4];
        float ls = 0.f;
        #pragma unroll
        for (int n = 0; n < 4; ++n)
            #pragma unroll
            for (int r = 0; r < 4; ++r) {
                float pv = __expf((sacc[n][r] - mx) * SCALE);
                p[n][r] = pv;
                ls += pv;
            }
        Lsum += ls;

        // ---- pack to bf16 dwords: D[n][h] = keys n*16 + g*4 + 2h + {0,1}
        unsigned D00 = cvtpk_bf16(p[0][0], p[0][1]), D01 = cvtpk_bf16(p[0][2], p[0][3]);
        unsigned D10 = cvtpk_bf16(p[1][0], p[1][1]), D11 = cvtpk_bf16(p[1][2], p[1][3]);
        unsigned D20 = cvtpk_bf16(p[2][0], p[2][1]), D21 = cvtpk_bf16(p[2][2], p[2][3]);
        unsigned D30 = cvtpk_bf16(p[3][0], p[3][1]), D31 = cvtpk_bf16(p[3][2], p[3][3]);

        // ---- 8-shfl conflict-free redistribution to PV A-frag layout
        unsigned r0 = __shfl((int)(lo ? D10 : D00), sA);
        unsigned r1 = __shfl((int)(lo ? D11 : D01), sA);
        unsigned r2 = __shfl((int)(lo ? D00 : D10), sB);
        unsigned r3 = __shfl((int)(lo ? D01 : D11), sB);
        unsigned r4 = __shfl((int)(lo ? D30 : D20), sA);
        unsigned r5 = __shfl((int)(lo ? D31 : D21), sA);
        unsigned r6 = __shfl((int)(lo ? D20 : D30), sB);
        unsigned r7 = __shfl((int)(lo ? D21 : D31), sB);
        i32x4 w0, w1;
        w0[0] = (int)(hb ? r2 : r0);  w0[1] = (int)(hb ? r3 : r1);
        w0[2] = (int)(hb ? r0 : r2);  w0[3] = (int)(hb ? r1 : r3);
        w1[0] = (int)(hb ? r6 : r4);  w1[1] = (int)(hb ? r7 : r5);
        w1[2] = (int)(hb ? r4 : r6);  w1[3] = (int)(hb ? r5 : r7);
        bf16x8 pa0 = __builtin_bit_cast(bf16x8, w0);
        bf16x8 pa1 = __builtin_bit_cast(bf16x8, w1);

        // ---- PV: oacc[n] += P(16q x 64k) * V(64k x 128d)
        __builtin_amdgcn_s_setprio(1);
        #pragma unroll
        for (int n = 0; n < 8; ++n) {
            bf16x8 bv = read_frag64(lvc, n * 16 + r15, g * 8);
            oacc[n] = mfma_bf16(pa0, bv, oacc[n]);
        }
        #pragma unroll
        for (int n = 0; n < 8; ++n) {
            bf16x8 bv = read_frag64(lvc, n * 16 + r15, 32 + g * 8);
            oacc[n] = mfma_bf16(pa1, bv, oacc[n]);
        }
        __builtin_amdgcn_s_setprio(0);

        asm volatile("s_waitcnt vmcnt(0)" ::: "memory");
        __builtin_amdgcn_s_barrier();
    }

    // ---- L reduce (q = r15), broadcast to O layout (q = 4g + r), store
    float L = Lsum;
    L += __shfl_xor(L, 16);
    L += __shfl_xor(L, 32);
    float inv = 1.0f / (L + 1e-6f);
    float invr[4];
    #pragma unroll
    for (int r = 0; r < 4; ++r)
        invr[r] = __shfl(inv, g * 4 + r);

    #pragma unroll
    for (int n = 0; n < 8; ++n) {
        int col = h * HD + n * 16 + r15;
        int rowb = qb * 128 + w * 16 + g * 4;
        #pragma unroll
        for (int r = 0; r < 4; ++r)
            Ob[(size_t)(rowb + r) * DM + col] = (bf16_t)(oacc[n][r] * invr[r]);
    }
}

extern "C" void kernel_launch(void* const* d_in, const int* in_sizes, int n_in,
                              void* d_out, int out_size, void* d_ws, size_t ws_size,
                              hipStream_t stream)
{
    const float* x    = (const float*)d_in[0];
    const float* fcos = (const float*)d_in[1];
    const float* fsin = (const float*)d_in[2];
    const float* Wq   = (const float*)d_in[3];
    const float* Wk   = (const float*)d_in[4];
    const float* Wv   = (const float*)d_in[5];
    const float* Wo   = (const float*)d_in[6];
    float* out = (float*)d_out;

    const size_t NE = (size_t)DM * SEQ;
    bf16_t* ws  = (bf16_t*)d_ws;
    bf16_t* xb  = ws;
    bf16_t* wqb = ws + 1 * NE;
    bf16_t* wkb = ws + 2 * NE;
    bf16_t* wvb = ws + 3 * NE;
    bf16_t* wob = ws + 4 * NE;
    bf16_t* qr  = ws + 5 * NE;
    bf16_t* kr  = ws + 6 * NE;
    bf16_t* vt  = ws + 7 * NE;
    bf16_t* ob  = ws + 8 * NE;

    hipLaunchKernelGGL(cvt5, dim3(4096, 5), dim3(256), 0, stream,
                       x, Wq, Wk, Wv, Wo, xb, wqb, wkb, wvb, wob);

    hipLaunchKernelGGL(qkv_pipe, dim3(8, 24), dim3(512), 0, stream,
                       xb, wqb, wkb, wvb, qr, kr, vt, fcos, fsin);

    hipLaunchKernelGGL(attn_k2, dim3(16, 16), dim3(512), 0, stream,
                       qr, kr, vt, ob);

    hipLaunchKernelGGL(gemm_fin, dim3(16, 16), dim3(256), 0, stream,
                       ob, wob, out);
}

// Round 7
// 179.743 us; speedup vs baseline: 1.2238x; 1.0184x over previous
//
#include <hip/hip_runtime.h>
#include <hip/hip_bf16.h>
#include <math.h>

#define SEQ 2048
#define DM  2048
#define NH  16
#define HD  128
#define SCALE 0.08838834764831845f

typedef __bf16 bf16_t;
typedef __bf16 bf16x8 __attribute__((ext_vector_type(8)));
typedef __bf16 bf16x4 __attribute__((ext_vector_type(4)));
typedef float  f32x4  __attribute__((ext_vector_type(4)));
typedef int    i32x4  __attribute__((ext_vector_type(4)));

typedef const __attribute__((address_space(1))) void* gas_ptr;
typedef __attribute__((address_space(3))) void* las_ptr;

__device__ __forceinline__ void gload_lds16(const void* g, void* l) {
    __builtin_amdgcn_global_load_lds((gas_ptr)g, (las_ptr)l, 16, 0, 0);
}

__device__ __forceinline__ f32x4 mfma_bf16(bf16x8 a, bf16x8 b, f32x4 c) {
    return __builtin_amdgcn_mfma_f32_16x16x32_bf16(a, b, c, 0, 0, 0);
}

__device__ __forceinline__ unsigned cvtpk_bf16(float lo, float hi) {
    unsigned d;
    asm("v_cvt_pk_bf16_f32 %0, %1, %2" : "=v"(d) : "v"(lo), "v"(hi));
    return d;
}

// LDS tile with 64 bf16 per row (128B): chunk (16B) XOR-swizzled by row&7
__device__ __forceinline__ bf16x8 read_frag64(const bf16_t* lds, int row, int k) {
    int chunk = (k >> 3) ^ (row & 7);
    return *(const bf16x8*)(lds + row * 64 + chunk * 8);
}
// LDS tile with 128 bf16 per row (256B): low 3 chunk bits swizzled
__device__ __forceinline__ bf16x8 read_frag128(const bf16_t* lds, int row, int k) {
    int chunk = k >> 3;
    chunk = (chunk & 8) | ((chunk ^ row) & 7);
    return *(const bf16x8*)(lds + row * 128 + chunk * 8);
}
// K-slab layout [256 rows][32 bf16], 16B slot-swizzled: phys j = kj ^ ((row>>1)&3)
__device__ __forceinline__ bf16x8 read_slab(const bf16_t* sl, int row, int g) {
    int j = g ^ ((row >> 1) & 3);
    return *(const bf16x8*)(sl + row * 32 + j * 8);
}

// ---------------- fp32 -> bf16 conversion (5 arrays of 2048*2048) -------------
__global__ __launch_bounds__(256) void cvt5(
    const float* __restrict__ s0, const float* __restrict__ s1,
    const float* __restrict__ s2, const float* __restrict__ s3,
    const float* __restrict__ s4,
    bf16_t* __restrict__ d0, bf16_t* __restrict__ d1, bf16_t* __restrict__ d2,
    bf16_t* __restrict__ d3, bf16_t* __restrict__ d4)
{
    int which = blockIdx.y;
    const float* s; bf16_t* d;
    switch (which) {
        case 0: s = s0; d = d0; break;
        case 1: s = s1; d = d1; break;
        case 2: s = s2; d = d2; break;
        case 3: s = s3; d = d3; break;
        default: s = s4; d = d4; break;
    }
    size_t idx = ((size_t)blockIdx.x * 256 + threadIdx.x) * 4;
    float4 v = *(const float4*)(s + idx);
    bf16x4 o = { (bf16_t)v.x, (bf16_t)v.y, (bf16_t)v.z, (bf16_t)v.w };
    *(bf16x4*)(d + idx) = o;
}

// ---------------- 8-phase pipelined QKV GEMM: 256x256, BK=64, 128KB LDS ------
#define BARX() asm volatile("s_barrier" ::: "memory")
#define VMW8 asm volatile("s_waitcnt vmcnt(8)" ::: "memory")
#define VMW4 asm volatile("s_waitcnt vmcnt(4)" ::: "memory")
#define VMW0 asm volatile("s_waitcnt vmcnt(0)" ::: "memory")
#define NOGATE

__global__ __launch_bounds__(512, 2) void qkv_pipe(
    const bf16_t* __restrict__ A,
    const bf16_t* __restrict__ B0, const bf16_t* __restrict__ B1,
    const bf16_t* __restrict__ B2,
    bf16_t* __restrict__ Oq, bf16_t* __restrict__ Ok, bf16_t* __restrict__ Ov,
    const float* __restrict__ fcos, const float* __restrict__ fsin)
{
    __shared__ bf16_t lds[65536];   // 128 KB

    const int tid = threadIdx.x;
    const int lane = tid & 63;
    const int w = tid >> 6;
    const int wm = w >> 2;           // 0..1
    const int wn = w & 3;            // 0..3
    const int g4 = lane >> 4, r15 = lane & 15;

    const int bm = blockIdx.x;       // 0..7
    const int bny = blockIdx.y;      // 0..23
    const int sel = bny >> 3;
    const int bnl = bny & 7;
    const bf16_t* Bp = (sel == 0) ? B0 : (sel == 1) ? B1 : B2;

    const size_t arow0 = (size_t)bm * 256;
    const size_t brow0 = (size_t)bnl * 256;

    const int row0 = tid >> 2;                    // c0 row (c1 row = row0+128)
    const int kj0  = (tid & 3) ^ ((row0 >> 1) & 3);
    const bf16_t* pA = A  + (arow0 + row0) * DM + kj0 * 8;
    const bf16_t* pB = Bp + (brow0 + row0) * DM + kj0 * 8;
    char* ldsb = (char*)lds;
    const int off0 = tid * 16;
    const int off1 = 8192 + tid * 16;

    #define STAGE_HT(S) do { if ((S) < 128) {                                   \
        const int T_ = (S) >> 2, a_ = (S) & 3;                                  \
        const int ko_ = T_ * 64 + ((a_ >> 1) << 5);                             \
        char* dst_ = ldsb + (((T_ & 1) << 16) | ((a_ & 1) << 15) | ((a_ >> 1) << 14)); \
        const bf16_t* s0_ = (a_ & 1) ? pB : pA;                                 \
        gload_lds16(s0_ + ko_, dst_ + off0);                                    \
        gload_lds16(s0_ + 128 * DM + ko_, dst_ + off1);                         \
    } } while (0)

    const bf16_t* b0A0 = lds;
    const bf16_t* b0A1 = lds + 8192;
    const bf16_t* b0B0 = lds + 16384;
    const bf16_t* b0B1 = lds + 24576;
    const bf16_t* b1A0 = lds + 32768;
    const bf16_t* b1A1 = lds + 40960;
    const bf16_t* b1B0 = lds + 49152;
    const bf16_t* b1B1 = lds + 57344;

    f32x4 acc[8][4] = {};

    #define PHASE(ASL, BSL, MH, SIDX, GATE, READB)                              \
    {                                                                           \
        _Pragma("unroll")                                                       \
        for (int m = 0; m < 4; ++m)                                             \
            af[m] = read_slab((ASL), wm * 128 + (MH) * 64 + m * 16 + r15, g4);  \
        if (READB) {                                                            \
            _Pragma("unroll")                                                   \
            for (int n = 0; n < 4; ++n)                                         \
                bfr[n] = read_slab((BSL), wn * 64 + n * 16 + r15, g4);          \
        }                                                                       \
        STAGE_HT(SIDX);                                                         \
        GATE;                                                                   \
        BARX();                                                                 \
        __builtin_amdgcn_s_setprio(1);                                          \
        _Pragma("unroll")                                                       \
        for (int m = 0; m < 4; ++m)                                             \
            _Pragma("unroll")                                                   \
            for (int n = 0; n < 4; ++n)                                         \
                acc[(MH) * 4 + m][n] = mfma_bf16(af[m], bfr[n], acc[(MH) * 4 + m][n]); \
        __builtin_amdgcn_s_setprio(0);                                          \
        BARX();                                                                 \
    }

    STAGE_HT(0); STAGE_HT(1); STAGE_HT(2); STAGE_HT(3); STAGE_HT(4); STAGE_HT(5);
    VMW8;
    BARX();

    for (int i = 0; i < 15; ++i) {
        const int s0 = 6 + i * 8;
        bf16x8 af[4], bfr[4];
        PHASE(b0A0, b0B0, 0, s0 + 0, NOGATE, 1)
        PHASE(b0A0, b0B0, 1, s0 + 1, VMW8,   0)
        PHASE(b0A1, b0B1, 0, s0 + 2, NOGATE, 1)
        PHASE(b0A1, b0B1, 1, s0 + 3, VMW8,   0)
        PHASE(b1A0, b1B0, 0, s0 + 4, NOGATE, 1)
        PHASE(b1A0, b1B0, 1, s0 + 5, VMW8,   0)
        PHASE(b1A1, b1B1, 0, s0 + 6, NOGATE, 1)
        PHASE(b1A1, b1B1, 1, s0 + 7, VMW8,   0)
    }
    {
        const int s0 = 6 + 15 * 8;
        bf16x8 af[4], bfr[4];
        PHASE(b0A0, b0B0, 0, s0 + 0, NOGATE, 1)
        PHASE(b0A0, b0B0, 1, s0 + 1, VMW8,   0)
        PHASE(b0A1, b0B1, 0, s0 + 2, NOGATE, 1)
        PHASE(b0A1, b0B1, 1, s0 + 3, VMW4,   0)
        PHASE(b1A0, b1B0, 0, s0 + 4, NOGATE, 1)
        PHASE(b1A0, b1B0, 1, s0 + 5, VMW0,   0)
        PHASE(b1A1, b1B1, 0, s0 + 6, NOGATE, 1)
        PHASE(b1A1, b1B1, 1, s0 + 7, NOGATE, 0)
    }
    #undef PHASE
    #undef STAGE_HT

    const int r0 = bm * 256 + wm * 128;
    const int c0 = bnl * 256 + wn * 64;

    if (sel == 2) {
        #pragma unroll
        for (int m = 0; m < 8; ++m) {
            int rowb = r0 + m * 16 + g4 * 4;
            #pragma unroll
            for (int n = 0; n < 4; ++n) {
                int col = c0 + n * 16 + r15;
                bf16x4 pk = { (bf16_t)acc[m][n][0], (bf16_t)acc[m][n][1],
                              (bf16_t)acc[m][n][2], (bf16_t)acc[m][n][3] };
                *(bf16x4*)&Ov[(size_t)col * SEQ + rowb] = pk;
            }
        }
    } else {
        bf16_t* dst = (sel == 0) ? Oq : Ok;
        #pragma unroll
        for (int m = 0; m < 8; ++m) {
            int rowb = r0 + m * 16 + g4 * 4;
            #pragma unroll
            for (int n = 0; n < 4; ++n) {
                int col = c0 + n * 16 + r15;
                int f = (col & (HD - 1)) >> 1;
                float sgn = (col & 1) ? 1.0f : -1.0f;
                #pragma unroll
                for (int r = 0; r < 4; ++r) {
                    float mine = acc[m][n][r];
                    float other = __shfl_xor(mine, 1);
                    float cc = fcos[(rowb + r) * (HD / 2) + f];
                    float ss = fsin[(rowb + r) * (HD / 2) + f];
                    float o = mine * cc + sgn * other * ss;
                    dst[(size_t)(rowb + r) * DM + col] = (bf16_t)o;
                }
            }
        }
    }
}

// ---------------- final projection GEMM (128x128 tile) -----------------------
__global__ __launch_bounds__(256) void gemm_fin(
    const bf16_t* __restrict__ A, const bf16_t* __restrict__ B0,
    float* __restrict__ Of)
{
    __shared__ bf16_t lA[128 * 64];
    __shared__ bf16_t lB[128 * 64];

    const int tid = threadIdx.x;
    const int lane = tid & 63;
    const int w = tid >> 6;
    const int wm = w >> 1, wn = w & 1;
    const int g = lane >> 4, r15 = lane & 15;

    const int bm = blockIdx.x;
    const int bn = blockIdx.y;

    f32x4 acc[4][4] = {};

    const size_t arow0 = (size_t)bm * 128;
    const size_t brow0 = (size_t)bn * 128;

    for (int kt = 0; kt < DM / 64; ++kt) {
        const int k0 = kt * 64;
        #pragma unroll
        for (int i = 0; i < 4; ++i) {
            int c = i * 256 + tid;
            int row = c >> 3;
            int ck = (c ^ row) & 7;
            const bf16_t* ga = A + (arow0 + row) * DM + k0 + ck * 8;
            gload_lds16(ga, (char*)lA + (i * 256 + w * 64) * 16);
            const bf16_t* gb = B0 + (brow0 + row) * DM + k0 + ck * 8;
            gload_lds16(gb, (char*)lB + (i * 256 + w * 64) * 16);
        }
        __syncthreads();
        #pragma unroll
        for (int kk = 0; kk < 2; ++kk) {
            bf16x8 af[4], bfr[4];
            #pragma unroll
            for (int m = 0; m < 4; ++m)
                af[m] = read_frag64(lA, wm * 64 + m * 16 + r15, kk * 32 + g * 8);
            #pragma unroll
            for (int n = 0; n < 4; ++n)
                bfr[n] = read_frag64(lB, wn * 64 + n * 16 + r15, kk * 32 + g * 8);
            #pragma unroll
            for (int m = 0; m < 4; ++m)
                #pragma unroll
                for (int n = 0; n < 4; ++n)
                    acc[m][n] = mfma_bf16(af[m], bfr[n], acc[m][n]);
        }
        __syncthreads();
    }

    const int r0 = bm * 128 + wm * 64;
    const int c0 = bn * 128 + wn * 64;
    #pragma unroll
    for (int m = 0; m < 4; ++m) {
        int rowb = r0 + m * 16 + g * 4;
        #pragma unroll
        for (int n = 0; n < 4; ++n) {
            int col = c0 + n * 16 + r15;
            #pragma unroll
            for (int r = 0; r < 4; ++r)
                Of[(size_t)(rowb + r) * DM + col] = acc[m][n][r];
        }
    }
}

// ---------------- attention v3: QBLK=64, 4 waves, 2 blocks/CU ----------------
// grid (32 q-blocks of 64, 16 heads), 256 thr = 4 waves, wave = 16 q-rows.
// K/V double-buffered in LDS (64KB -> 2 blocks/CU); Q in registers;
// swapped QK^T, in-register P transpose; single barrier per j-iter.
__global__ __launch_bounds__(256, 2) void attn_k2(
    const bf16_t* __restrict__ Q, const bf16_t* __restrict__ Kb,
    const bf16_t* __restrict__ Vt, bf16_t* __restrict__ Ob)
{
    __shared__ bf16_t lk[2 * 64 * 128];   // K tiles (double buffer), read_frag128 layout
    __shared__ bf16_t lv[2 * 128 * 64];   // V^T tiles (double buffer), read_frag64 layout

    const int tid = threadIdx.x;
    const int lane = tid & 63;
    const int w = tid >> 6;              // wave id 0..3: q-rows w*16..w*16+15
    const int g = lane >> 4, r15 = lane & 15;
    const int qb = blockIdx.x, h = blockIdx.y;

    const int lo = g & 1, hb = g >> 1;
    const int e_src = (lo << 5) + r15;   // even-parity source lane (g_s = 2*lo)
    const int o_src = e_src + 16;        // odd-parity source lane (g_s = 2*lo+1)
    const int sA = hb ? o_src : e_src;
    const int sB = hb ? e_src : o_src;

    // Q fragments (B-operand): Q[q = qb*64 + w*16 + r15][d = ks*32 + g*8 + j]
    bf16x8 qf[4];
    {
        const bf16_t* qrow = Q + (size_t)(qb * 64 + w * 16 + r15) * DM + h * HD + g * 8;
        #pragma unroll
        for (int ks = 0; ks < 4; ++ks)
            qf[ks] = *(const bf16x8*)(qrow + ks * 32);
    }

    f32x4 oacc[8] = {};
    float Lsum = 0.f;

    // K tile: 1024 16B chunks; V^T tile: 1024 16B chunks (256 threads, 4 groups)
    #define STAGE_KV(JJ, BUF)                                                     \
    {                                                                             \
        _Pragma("unroll")                                                         \
        for (int i = 0; i < 4; ++i) {                                             \
            int c = i * 256 + tid;                                                \
            int row = c >> 4, ckl = c & 15;                                       \
            int ck = (ckl & 8) | ((ckl ^ row) & 7);                               \
            const bf16_t* gk = Kb + (size_t)((JJ) * 64 + row) * DM + h * HD + ck * 8; \
            gload_lds16(gk, (char*)lk + (BUF) * 16384 + (i * 256 + w * 64) * 16); \
        }                                                                         \
        _Pragma("unroll")                                                         \
        for (int i = 0; i < 4; ++i) {                                             \
            int c = i * 256 + tid;                                                \
            int row = c >> 3;                                                     \
            int ck = (c ^ row) & 7;                                               \
            const bf16_t* gv = Vt + (size_t)(h * HD + row) * SEQ + (JJ) * 64 + ck * 8; \
            gload_lds16(gv, (char*)lv + (BUF) * 16384 + (i * 256 + w * 64) * 16); \
        }                                                                         \
    }

    STAGE_KV(0, 0);
    asm volatile("s_waitcnt vmcnt(0)" ::: "memory");
    __builtin_amdgcn_s_barrier();

    for (int j = 0; j < SEQ / 64; ++j) {
        const int cur = j & 1;
        const bf16_t* lkc = lk + cur * 8192;
        const bf16_t* lvc = lv + cur * 8192;
        if (j < SEQ / 64 - 1) STAGE_KV(j + 1, cur ^ 1);

        // ---- QK^T swapped: sacc[n][r] = S[key = n*16+g*4+r][q = w*16+r15]
        f32x4 sacc[4] = {};
        __builtin_amdgcn_s_setprio(1);
        #pragma unroll
        for (int ks = 0; ks < 4; ++ks) {
            #pragma unroll
            for (int n = 0; n < 4; ++n) {
                bf16x8 kf = read_frag128(lkc, n * 16 + r15, ks * 32 + g * 8);
                sacc[n] = mfma_bf16(kf, qf[ks], sacc[n]);
            }
        }
        __builtin_amdgcn_s_setprio(0);

        // ---- block-local softmax for q = r15 (64 keys spread over g groups)
        float mx0 = fmaxf(fmaxf(sacc[0][0], sacc[0][1]), fmaxf(sacc[0][2], sacc[0][3]));
        float mx1 = fmaxf(fmaxf(sacc[1][0], sacc[1][1]), fmaxf(sacc[1][2], sacc[1][3]));
        float mx2 = fmaxf(fmaxf(sacc[2][0], sacc[2][1]), fmaxf(sacc[2][2], sacc[2][3]));
        float mx3 = fmaxf(fmaxf(sacc[3][0], sacc[3][1]), fmaxf(sacc[3][2], sacc[3][3]));
        float mx = fmaxf(fmaxf(mx0, mx1), fmaxf(mx2, mx3));
        mx = fmaxf(mx, __shfl_xor(mx, 16));
        mx = fmaxf(mx, __shfl_xor(mx, 32));

        float p[4][4];
        float ls = 0.f;
        #pragma unroll
        for (int n = 0; n < 4; ++n)
            #pragma unroll
            for (int r = 0; r < 4; ++r) {
                float pv = __expf((sacc[n][r] - mx) * SCALE);
                p[n][r] = pv;
                ls += pv;
            }
        Lsum += ls;

        // ---- pack to bf16 dwords: D[n][h] = keys n*16 + g*4 + 2h + {0,1}
        unsigned D00 = cvtpk_bf16(p[0][0], p[0][1]), D01 = cvtpk_bf16(p[0][2], p[0][3]);
        unsigned D10 = cvtpk_bf16(p[1][0], p[1][1]), D11 = cvtpk_bf16(p[1][2], p[1][3]);
        unsigned D20 = cvtpk_bf16(p[2][0], p[2][1]), D21 = cvtpk_bf16(p[2][2], p[2][3]);
        unsigned D30 = cvtpk_bf16(p[3][0], p[3][1]), D31 = cvtpk_bf16(p[3][2], p[3][3]);

        // ---- 8-shfl conflict-free redistribution to PV A-frag layout
        unsigned r0 = __shfl((int)(lo ? D10 : D00), sA);
        unsigned r1 = __shfl((int)(lo ? D11 : D01), sA);
        unsigned r2 = __shfl((int)(lo ? D00 : D10), sB);
        unsigned r3 = __shfl((int)(lo ? D01 : D11), sB);
        unsigned r4 = __shfl((int)(lo ? D30 : D20), sA);
        unsigned r5 = __shfl((int)(lo ? D31 : D21), sA);
        unsigned r6 = __shfl((int)(lo ? D20 : D30), sB);
        unsigned r7 = __shfl((int)(lo ? D21 : D31), sB);
        i32x4 w0, w1;
        w0[0] = (int)(hb ? r2 : r0);  w0[1] = (int)(hb ? r3 : r1);
        w0[2] = (int)(hb ? r0 : r2);  w0[3] = (int)(hb ? r1 : r3);
        w1[0] = (int)(hb ? r6 : r4);  w1[1] = (int)(hb ? r7 : r5);
        w1[2] = (int)(hb ? r4 : r6);  w1[3] = (int)(hb ? r5 : r7);
        bf16x8 pa0 = __builtin_bit_cast(bf16x8, w0);
        bf16x8 pa1 = __builtin_bit_cast(bf16x8, w1);

        // ---- PV: oacc[n] += P(16q x 64k) * V(64k x 128d)
        __builtin_amdgcn_s_setprio(1);
        #pragma unroll
        for (int n = 0; n < 8; ++n) {
            bf16x8 bv = read_frag64(lvc, n * 16 + r15, g * 8);
            oacc[n] = mfma_bf16(pa0, bv, oacc[n]);
        }
        #pragma unroll
        for (int n = 0; n < 8; ++n) {
            bf16x8 bv = read_frag64(lvc, n * 16 + r15, 32 + g * 8);
            oacc[n] = mfma_bf16(pa1, bv, oacc[n]);
        }
        __builtin_amdgcn_s_setprio(0);

        asm volatile("s_waitcnt vmcnt(0)" ::: "memory");
        __builtin_amdgcn_s_barrier();
    }

    // ---- L reduce (q = r15), broadcast to O layout (q = 4g + r), store
    float L = Lsum;
    L += __shfl_xor(L, 16);
    L += __shfl_xor(L, 32);
    float inv = 1.0f / (L + 1e-6f);
    float invr[4];
    #pragma unroll
    for (int r = 0; r < 4; ++r)
        invr[r] = __shfl(inv, g * 4 + r);

    #pragma unroll
    for (int n = 0; n < 8; ++n) {
        int col = h * HD + n * 16 + r15;
        int rowb = qb * 64 + w * 16 + g * 4;
        #pragma unroll
        for (int r = 0; r < 4; ++r)
            Ob[(size_t)(rowb + r) * DM + col] = (bf16_t)(oacc[n][r] * invr[r]);
    }
}

extern "C" void kernel_launch(void* const* d_in, const int* in_sizes, int n_in,
                              void* d_out, int out_size, void* d_ws, size_t ws_size,
                              hipStream_t stream)
{
    const float* x    = (const float*)d_in[0];
    const float* fcos = (const float*)d_in[1];
    const float* fsin = (const float*)d_in[2];
    const float* Wq   = (const float*)d_in[3];
    const float* Wk   = (const float*)d_in[4];
    const float* Wv   = (const float*)d_in[5];
    const float* Wo   = (const float*)d_in[6];
    float* out = (float*)d_out;

    const size_t NE = (size_t)DM * SEQ;
    bf16_t* ws  = (bf16_t*)d_ws;
    bf16_t* xb  = ws;
    bf16_t* wqb = ws + 1 * NE;
    bf16_t* wkb = ws + 2 * NE;
    bf16_t* wvb = ws + 3 * NE;
    bf16_t* wob = ws + 4 * NE;
    bf16_t* qr  = ws + 5 * NE;
    bf16_t* kr  = ws + 6 * NE;
    bf16_t* vt  = ws + 7 * NE;
    bf16_t* ob  = ws + 8 * NE;

    hipLaunchKernelGGL(cvt5, dim3(4096, 5), dim3(256), 0, stream,
                       x, Wq, Wk, Wv, Wo, xb, wqb, wkb, wvb, wob);

    hipLaunchKernelGGL(qkv_pipe, dim3(8, 24), dim3(512), 0, stream,
                       xb, wqb, wkb, wvb, qr, kr, vt, fcos, fsin);

    hipLaunchKernelGGL(attn_k2, dim3(32, 16), dim3(256), 0, stream,
                       qr, kr, vt, ob);

    hipLaunchKernelGGL(gemm_fin, dim3(16, 16), dim3(256), 0, stream,
                       ob, wob, out);
}